// Round 8
// baseline (1018.094 us; speedup 1.0000x reference)
//
#include <hip/hip_runtime.h>

#define NN 50000
#define NE 800000
#define FD 128
#define FA 32
#define NG 128
#define EETOT (NE + NN)

// ---------- bf16 helpers, pure bit ops ----------
__device__ __forceinline__ float bfbits(unsigned short u) {
    return __uint_as_float(((unsigned int)u) << 16);
}
__device__ __forceinline__ float bflo(unsigned int p) { return __uint_as_float(p << 16); }
__device__ __forceinline__ float bfhi(unsigned int p) { return __uint_as_float(p & 0xffff0000u); }
__device__ __forceinline__ unsigned short f2bf(float f) {   // RNE
    unsigned int u = __float_as_uint(f);
    unsigned int r = u + 0x7FFFu + ((u >> 16) & 1u);
    return (unsigned short)(r >> 16);
}
__device__ __forceinline__ int ld_idx(const int* p, int i, int is64) {
    return is64 ? p[2 * i] : p[i];
}

// ---------- sentinels: 128 fp32 words (512B — safe for either out dtype) ----------
__global__ __launch_bounds__(128) void mark_kernel(float* out, float v) {
    out[threadIdx.x] = v;
}
__global__ __launch_bounds__(256) void zero_i32(int* p, int n) {
    int i = blockIdx.x * 256 + threadIdx.x;
    if (i < n) p[i] = 0;
}
__global__ __launch_bounds__(256) void zero_f32(float* p, int n) {
    int i = blockIdx.x * 256 + threadIdx.x;
    if (i < n) p[i] = 0.0f;
}

// ---------- dtype detection ----------
__global__ __launch_bounds__(64) void detect_ft(const unsigned int* t, int nwords,
                                                int* flagout) {
    if (threadIdx.x == 0) {
        int nz = 0, hits = 0;
        for (int i = 0; i < nwords; ++i) {
            unsigned int w = t[i];
            if (w == 0u) continue;
            ++nz;
            unsigned int e = (w >> 7) & 0xFFu;
            if (e >= 100u && e <= 140u) ++hits;
        }
        *flagout = (nz < 8) ? 1 : (hits * 4 >= nz * 3);
    }
}
__global__ __launch_bounds__(64) void detect_ie(const int* ei, int* flagout) {
    if (threadIdx.x == 0) {
        int odd_or = 0;
        for (int k = 0; k < 32; ++k) odd_or |= ei[2 * k + 1];
        *flagout = (odd_or == 0) ? 1 : 0;
    }
}
__global__ __launch_bounds__(64) void detect_b(const int* b, int* flagout) {
    if (threadIdx.x == 0) *flagout = (b[NN - 1] == 0) ? 1 : 0;
}

// ---------- canonicalize weights ----------
__global__ __launch_bounds__(256) void cvt_f32(const void* src, const int* flag,
                                               float* dst, int n) {
    int i = blockIdx.x * 256 + threadIdx.x;
    if (i >= n) return;
    if (*flag) dst[i] = bfbits(((const unsigned short*)src)[i]);
    else       dst[i] = ((const float*)src)[i];
}
__global__ __launch_bounds__(256) void cvt_bf(const void* src, const int* flag,
                                              unsigned int* dst, int npairs) {
    int i = blockIdx.x * 256 + threadIdx.x;
    if (i >= npairs) return;
    if (*flag) {
        dst[i] = ((const unsigned int*)src)[i];
    } else {
        const float* s = (const float*)src;
        unsigned int lo = f2bf(s[2 * i]);
        unsigned int hi = f2bf(s[2 * i + 1]);
        dst[i] = lo | (hi << 16);
    }
}

// ---------- graph preprocessing ----------
__global__ __launch_bounds__(256) void deg_kernel(const int* ei, const int* iflag,
                                                  int* deg) {
    int e = blockIdx.x * 256 + threadIdx.x;
    int is64 = *iflag;
    if (e < NE) atomicAdd(&deg[ld_idx(ei, NE + e, is64)], 1);
}
__global__ __launch_bounds__(256) void dinv_kernel(const int* deg, float* dinv) {
    int i = blockIdx.x * 256 + threadIdx.x;
    if (i < NN) dinv[i] = rsqrtf((float)(deg[i] + 1));
}
__global__ __launch_bounds__(1024) void scan_kernel(const int* deg, int* rowstart,
                                                    int* cursor) {
    __shared__ int part[1024];
    const int T = 1024;
    const int chunk = (NN + T - 1) / T;
    int s = threadIdx.x * chunk;
    int e = s + chunk;
    if (e > NN) e = NN;
    if (s > NN) s = NN;
    int sum = 0;
    for (int i = s; i < e; ++i) sum += deg[i] + 1;
    part[threadIdx.x] = sum;
    __syncthreads();
    for (int off = 1; off < T; off <<= 1) {
        int v = part[threadIdx.x];
        int a = ((int)threadIdx.x >= off) ? part[threadIdx.x - off] : 0;
        __syncthreads();
        part[threadIdx.x] = v + a;
        __syncthreads();
    }
    int excl = (threadIdx.x == 0) ? 0 : part[threadIdx.x - 1];
    for (int i = s; i < e; ++i) {
        rowstart[i] = excl;
        cursor[i]   = excl;
        excl += deg[i] + 1;
    }
    if (threadIdx.x == T - 1) rowstart[NN] = excl;
}
__global__ __launch_bounds__(256) void fill_kernel(const int* ei, const int* iflag,
        const float* dinv, int* cursor, int* col, float* val) {
    int e = blockIdx.x * 256 + threadIdx.x;
    if (e >= EETOT) return;
    int is64 = *iflag;
    int s, d;
    if (e < NE) { s = ld_idx(ei, e, is64); d = ld_idx(ei, NE + e, is64); }
    else        { s = d = e - NE; }
    int pos = atomicAdd(&cursor[d], 1);
    col[pos] = s;
    val[pos] = dinv[s] * dinv[d];
}

// ---------- GEMMs: JAX LAYOUT — W (in,out) row-major, C = A @ W ----------
__global__ __launch_bounds__(256) void gemm1(const void* Ap, const int* xflag,
        const unsigned int* Wp, float* C) {
    __shared__ unsigned int Ws[FD * FD / 2];
    __shared__ float As[8][FD];
    for (int i = threadIdx.x; i < FD * FD / 2; i += 256) Ws[i] = Wp[i];
    int ar = threadIdx.x >> 5;
    int ac = (threadIdx.x & 31) * 4;
    int grow = blockIdx.x * 8 + ar;
    if (grow < NN) {
        if (*xflag) {
            const unsigned int* A = (const unsigned int*)Ap;
            unsigned int w0 = A[((size_t)grow * FD + ac) / 2];
            unsigned int w1 = A[((size_t)grow * FD + ac) / 2 + 1];
            As[ar][ac + 0] = bflo(w0); As[ar][ac + 1] = bfhi(w0);
            As[ar][ac + 2] = bflo(w1); As[ar][ac + 3] = bfhi(w1);
        } else {
            const float* A = (const float*)Ap;
            size_t b = (size_t)grow * FD + ac;
            As[ar][ac + 0] = A[b + 0]; As[ar][ac + 1] = A[b + 1];
            As[ar][ac + 2] = A[b + 2]; As[ar][ac + 3] = A[b + 3];
        }
    }
    __syncthreads();
    float a0 = 0.f, a1 = 0.f, a2 = 0.f, a3 = 0.f;
    #pragma unroll 8
    for (int k = 0; k < FD; ++k) {
        float a = As[ar][k];
        unsigned int w0 = Ws[(k * FD + ac) / 2];
        unsigned int w1 = Ws[(k * FD + ac) / 2 + 1];
        a0 += a * bflo(w0);
        a1 += a * bfhi(w0);
        a2 += a * bflo(w1);
        a3 += a * bfhi(w1);
    }
    if (grow < NN) {
        size_t b = (size_t)grow * FD + ac;
        C[b + 0] = a0; C[b + 1] = a1; C[b + 2] = a2; C[b + 3] = a3;
    }
}
__global__ __launch_bounds__(256) void gemm2(const float* A, const unsigned int* Wp,
                                             float* C) {
    __shared__ unsigned int Ws[FD * FD / 2];
    __shared__ float As[8][FD];
    for (int i = threadIdx.x; i < FD * FD / 2; i += 256) Ws[i] = Wp[i];
    int ar = threadIdx.x >> 5;
    int ac = (threadIdx.x & 31) * 4;
    int grow = blockIdx.x * 8 + ar;
    if (grow < NN) {
        size_t b = (size_t)grow * FD + ac;
        As[ar][ac + 0] = A[b + 0]; As[ar][ac + 1] = A[b + 1];
        As[ar][ac + 2] = A[b + 2]; As[ar][ac + 3] = A[b + 3];
    }
    __syncthreads();
    float a0 = 0.f, a1 = 0.f, a2 = 0.f, a3 = 0.f;
    #pragma unroll 8
    for (int k = 0; k < FD; ++k) {
        float a = As[ar][k];
        unsigned int w0 = Ws[(k * FD + ac) / 2];
        unsigned int w1 = Ws[(k * FD + ac) / 2 + 1];
        a0 += a * bflo(w0);
        a1 += a * bfhi(w0);
        a2 += a * bflo(w1);
        a3 += a * bfhi(w1);
    }
    if (grow < NN) {
        size_t b = (size_t)grow * FD + ac;
        C[b + 0] = a0; C[b + 1] = a1; C[b + 2] = a2; C[b + 3] = a3;
    }
}

// ---------- CSR aggregation + bias + relu ----------
__global__ __launch_bounds__(256) void aggregate_kernel(const float* H, const int* col,
        const float* val, const int* rowstart, const float* bias, float* out) {
    int n = blockIdx.x * 2 + (threadIdx.x >> 7);
    int c = threadIdx.x & 127;
    if (n >= NN) return;
    int jb = rowstart[n], je = rowstart[n + 1];
    float acc = 0.f;
    for (int j = jb; j < je; ++j)
        acc += val[j] * H[(size_t)col[j] * FD + c];
    acc += bias[c];
    out[(size_t)n * FD + c] = fmaxf(acc, 0.f);
}

// ---------- mean-pool partials ----------
__global__ __launch_bounds__(256) void pool_kernel(const float* H, const int* batch,
        const int* bflag, float* sums, float* counts) {
    int n = blockIdx.x * 2 + (threadIdx.x >> 7);
    int c = threadIdx.x & 127;
    if (n >= NN) return;
    int is64 = *bflag;
    int g = ld_idx(batch, n, is64);
    atomicAdd(&sums[g * FD + c], H[(size_t)n * FD + c]);
    if (c == 0) atomicAdd(&counts[g], 1.0f);
}

// ---------- head: JAX layout; OUTPUT dtype adaptive (fp32 unless inputs bf16) ----------
__global__ __launch_bounds__(128) void head_kernel(const float* sums, const float* counts,
        const float* addf, const float* fc1w, const float* fc1b,
        const float* fc2w, const float* fc2b, const int* xflag, void* outp) {
    int g = blockIdx.x;
    int t = threadIdx.x;
    __shared__ float z[FD + FA];
    __shared__ float h[FD];
    float cnt = counts[g];
    if (cnt < 1.0f) cnt = 1.0f;
    z[t] = sums[g * FD + t] / cnt;
    if (t < FA) z[FD + t] = addf[g * FA + t];
    __syncthreads();
    float acc = fc1b[t];
    #pragma unroll 4
    for (int k = 0; k < FD + FA; ++k)
        acc += z[k] * fc1w[k * FD + t];
    h[t] = fmaxf(acc, 0.f);
    __syncthreads();
    if (t < 2) {
        float o = fc2b[t];
        for (int j = 0; j < FD; ++j) o += h[j] * fc2w[j * 2 + t];
        if (*xflag) ((unsigned short*)outp)[g * 2 + t] = f2bf(o);
        else        ((float*)outp)[g * 2 + t] = o;
    }
}

extern "C" void kernel_launch(void* const* d_in, const int* in_sizes, int n_in,
                              void* d_out, int out_size, void* d_ws, size_t ws_size,
                              hipStream_t stream) {
    (void)out_size;

    if (n_in != 12) {
        hipLaunchKernelGGL(mark_kernel, dim3(1), dim3(128), 0, stream,
                           (float*)d_out, 2000.0f);
        return;
    }
    const int exp_sizes[12] = {6400000, 1600000, 50000, 4096, 16384, 128,
                               16384, 128, 20480, 128, 256, 2};
    for (int i = 0; i < 12; ++i) {
        if (in_sizes[i] != exp_sizes[i]) {
            hipLaunchKernelGGL(mark_kernel, dim3(1), dim3(128), 0, stream,
                               (float*)d_out, 3000.0f + 100.0f * i);
            return;
        }
    }

    size_t off = 0;
    char* base = (char*)d_ws;
#define WSALLOC(ptr, type, nbytes) \
    type* ptr = (type*)(base + off); off += (((size_t)(nbytes)) + 255) & ~(size_t)255;
    WSALLOC(bufA,  float, (size_t)NN * FD * 4)
    WSALLOC(bufB,  float, (size_t)NN * FD * 4)
    WSALLOC(dinv,  float, (size_t)NN * 4)
    WSALLOC(degi,  int,   (size_t)NN * 4)
    WSALLOC(rowst, int,   (size_t)(NN + 1) * 4)
    WSALLOC(cursor,int,   (size_t)NN * 4)
    WSALLOC(col,   int,   (size_t)EETOT * 4)
    WSALLOC(val,   float, (size_t)EETOT * 4)
    WSALLOC(sums,  float, (size_t)(NG * FD + NG) * 4)
    float* counts = sums + NG * FD;
    WSALLOC(W1p,   unsigned int, (size_t)FD * FD / 2 * 4)
    WSALLOC(W2p,   unsigned int, (size_t)FD * FD / 2 * 4)
    WSALLOC(b1f,   float, FD * 4)
    WSALLOC(b2f,   float, FD * 4)
    WSALLOC(addff, float, (size_t)NG * FA * 4)
    WSALLOC(fc1wf, float, (size_t)(FD + FA) * FD * 4)
    WSALLOC(fc1bf, float, FD * 4)
    WSALLOC(fc2wf, float, FD * 2 * 4)
    WSALLOC(fc2bf, float, 2 * 4)
    WSALLOC(flags, int, 16 * 4)
#undef WSALLOC
    if (ws_size < off) {
        hipLaunchKernelGGL(mark_kernel, dim3(1), dim3(128), 0, stream,
                           (float*)d_out, 1000.0f);
        return;
    }

    const int* ei    = (const int*)d_in[1];
    const int* batch = (const int*)d_in[2];

    hipLaunchKernelGGL(zero_i32, dim3(1), dim3(256), 0, stream, flags, 16);

    const int fidx[10] = {0, 3, 4, 5, 6, 7, 8, 9, 10, 11};
    for (int k = 0; k < 10; ++k) {
        int n = exp_sizes[fidx[k]];
        int nw = n / 2; if (nw > 64) nw = 64; if (nw < 1) nw = 1;
        hipLaunchKernelGGL(detect_ft, dim3(1), dim3(64), 0, stream,
                           (const unsigned int*)d_in[fidx[k]], nw, flags + fidx[k]);
    }
    hipLaunchKernelGGL(detect_ie, dim3(1), dim3(64), 0, stream, ei, flags + 12);
    hipLaunchKernelGGL(detect_b,  dim3(1), dim3(64), 0, stream, batch, flags + 13);

    hipLaunchKernelGGL(cvt_bf,  dim3((FD*FD/2 + 255)/256), dim3(256), 0, stream,
                       d_in[4], flags + 4, W1p, FD*FD/2);
    hipLaunchKernelGGL(cvt_bf,  dim3((FD*FD/2 + 255)/256), dim3(256), 0, stream,
                       d_in[6], flags + 6, W2p, FD*FD/2);
    hipLaunchKernelGGL(cvt_f32, dim3(1), dim3(256), 0, stream, d_in[5], flags + 5, b1f, FD);
    hipLaunchKernelGGL(cvt_f32, dim3(1), dim3(256), 0, stream, d_in[7], flags + 7, b2f, FD);
    hipLaunchKernelGGL(cvt_f32, dim3((NG*FA + 255)/256), dim3(256), 0, stream,
                       d_in[3], flags + 3, addff, NG*FA);
    hipLaunchKernelGGL(cvt_f32, dim3(((FD+FA)*FD + 255)/256), dim3(256), 0, stream,
                       d_in[8], flags + 8, fc1wf, (FD+FA)*FD);
    hipLaunchKernelGGL(cvt_f32, dim3(1), dim3(256), 0, stream, d_in[9], flags + 9, fc1bf, FD);
    hipLaunchKernelGGL(cvt_f32, dim3(1), dim3(256), 0, stream, d_in[10], flags + 10, fc2wf, FD*2);
    hipLaunchKernelGGL(cvt_f32, dim3(1), dim3(256), 0, stream, d_in[11], flags + 11, fc2bf, 2);

    hipLaunchKernelGGL(zero_i32, dim3((NN + 255)/256), dim3(256), 0, stream, degi, NN);
    hipLaunchKernelGGL(zero_f32, dim3((NG*FD + NG + 255)/256), dim3(256), 0, stream,
                       sums, NG*FD + NG);
    hipLaunchKernelGGL(deg_kernel, dim3((NE + 255)/256), dim3(256), 0, stream,
                       ei, flags + 12, degi);
    hipLaunchKernelGGL(dinv_kernel, dim3((NN + 255)/256), dim3(256), 0, stream,
                       degi, dinv);
    hipLaunchKernelGGL(scan_kernel, dim3(1), dim3(1024), 0, stream, degi, rowst, cursor);
    hipLaunchKernelGGL(fill_kernel, dim3((EETOT + 255)/256), dim3(256), 0, stream,
                       ei, flags + 12, dinv, cursor, col, val);

    hipLaunchKernelGGL(gemm1, dim3((NN + 7)/8), dim3(256), 0, stream,
                       d_in[0], flags + 0, W1p, bufA);
    hipLaunchKernelGGL(aggregate_kernel, dim3(NN/2), dim3(256), 0, stream,
                       bufA, col, val, rowst, b1f, bufB);
    hipLaunchKernelGGL(gemm2, dim3((NN + 7)/8), dim3(256), 0, stream, bufB, W2p, bufA);
    hipLaunchKernelGGL(aggregate_kernel, dim3(NN/2), dim3(256), 0, stream,
                       bufA, col, val, rowst, b2f, bufB);

    hipLaunchKernelGGL(pool_kernel, dim3(NN/2), dim3(256), 0, stream,
                       bufB, batch, flags + 13, sums, counts);
    hipLaunchKernelGGL(head_kernel, dim3(NG), dim3(FD), 0, stream,
                       sums, counts, addff, fc1wf, fc1bf, fc2wf, fc2bf,
                       flags + 0, d_out);
}

// Round 9
// 750.346 us; speedup vs baseline: 1.3568x; 1.3568x over previous
//
#include <hip/hip_runtime.h>

#define NN 50000
#define NE 800000
#define FD 128
#define FA 32
#define NG 128
#define EETOT (NE + NN)

// ---------- bf16 helpers, pure bit ops ----------
__device__ __forceinline__ float bfbits(unsigned short u) {
    return __uint_as_float(((unsigned int)u) << 16);
}
__device__ __forceinline__ float bflo(unsigned int p) { return __uint_as_float(p << 16); }
__device__ __forceinline__ float bfhi(unsigned int p) { return __uint_as_float(p & 0xffff0000u); }
__device__ __forceinline__ unsigned short f2bf(float f) {   // RNE
    unsigned int u = __float_as_uint(f);
    unsigned int r = u + 0x7FFFu + ((u >> 16) & 1u);
    return (unsigned short)(r >> 16);
}
__device__ __forceinline__ int ld_idx(const int* p, int i, int is64) {
    return is64 ? p[2 * i] : p[i];
}

// ---------- sentinels ----------
__global__ __launch_bounds__(128) void mark_kernel(float* out, float v) {
    out[threadIdx.x] = v;
}
__global__ __launch_bounds__(256) void zero_i32(int* p, int n) {
    int i = blockIdx.x * 256 + threadIdx.x;
    if (i < n) p[i] = 0;
}

// ---------- all dtype detection in one launch (12 blocks) ----------
__global__ __launch_bounds__(64) void detect_all(
        const unsigned int* x, const int* ei, const int* batch,
        const unsigned int* addf, const unsigned int* w1, const unsigned int* b1,
        const unsigned int* w2, const unsigned int* b2, const unsigned int* fc1w,
        const unsigned int* fc1b, const unsigned int* fc2w, const unsigned int* fc2b,
        const int* bflag_probe_unused, int* flags) {
    (void)bflag_probe_unused;
    if (threadIdx.x != 0) return;
    int b = blockIdx.x;
    if (b < 10) {
        const unsigned int* t = x; int nw = 64; int idx = 0;
        switch (b) {
            case 0: t = x;    nw = 64; idx = 0;  break;
            case 1: t = addf; nw = 64; idx = 3;  break;
            case 2: t = w1;   nw = 64; idx = 4;  break;
            case 3: t = b1;   nw = 64; idx = 5;  break;
            case 4: t = w2;   nw = 64; idx = 6;  break;
            case 5: t = b2;   nw = 64; idx = 7;  break;
            case 6: t = fc1w; nw = 64; idx = 8;  break;
            case 7: t = fc1b; nw = 64; idx = 9;  break;
            case 8: t = fc2w; nw = 64; idx = 10; break;
            case 9: t = fc2b; nw = 1;  idx = 11; break;
        }
        int nz = 0, hits = 0;
        for (int i = 0; i < nw; ++i) {
            unsigned int w = t[i];
            if (w == 0u) continue;
            ++nz;
            unsigned int e = (w >> 7) & 0xFFu;
            if (e >= 100u && e <= 140u) ++hits;
        }
        flags[idx] = (nz < 8) ? 1 : (hits * 4 >= nz * 3);
    } else if (b == 10) {
        int odd_or = 0;
        for (int k = 0; k < 32; ++k) odd_or |= ei[2 * k + 1];
        flags[12] = (odd_or == 0) ? 1 : 0;
    } else {
        flags[13] = (batch[NN - 1] == 0) ? 1 : 0;   // sorted: tail nonzero iff int32
    }
}

// ---------- canonicalize all fp32-destination weights in one launch ----------
// segments: addf[0,4096) b1[4096,4224) b2[4224,4352) fc1w[4352,24832)
//           fc1b[24832,24960) fc2w[24960,25216) fc2b[25216,25218)
__global__ __launch_bounds__(256) void cvt_f32_all(
        const void* addf, const void* b1, const void* b2, const void* fc1w,
        const void* fc1b, const void* fc2w, const void* fc2b, const int* flags,
        float* addff, float* b1f, float* b2f, float* fc1wf,
        float* fc1bf, float* fc2wf, float* fc2bf) {
    int i = blockIdx.x * 256 + threadIdx.x;
    const void* src; float* dst; int flag; int rel;
    if      (i < 4096)  { src = addf; dst = addff; flag = flags[3];  rel = i; }
    else if (i < 4224)  { src = b1;   dst = b1f;   flag = flags[5];  rel = i - 4096; }
    else if (i < 4352)  { src = b2;   dst = b2f;   flag = flags[7];  rel = i - 4224; }
    else if (i < 24832) { src = fc1w; dst = fc1wf; flag = flags[8];  rel = i - 4352; }
    else if (i < 24960) { src = fc1b; dst = fc1bf; flag = flags[9];  rel = i - 24832; }
    else if (i < 25216) { src = fc2w; dst = fc2wf; flag = flags[10]; rel = i - 24960; }
    else if (i < 25218) { src = fc2b; dst = fc2bf; flag = flags[11]; rel = i - 25216; }
    else return;
    if (flag) dst[rel] = bfbits(((const unsigned short*)src)[rel]);
    else      dst[rel] = ((const float*)src)[rel];
}

// ---------- canonicalize W1/W2 to packed bf16 in one launch ----------
__global__ __launch_bounds__(256) void cvt_bf_all(const void* w1, const void* w2,
        const int* flags, unsigned int* W1p, unsigned int* W2p) {
    int i = blockIdx.x * 256 + threadIdx.x;
    const void* src; unsigned int* dst; int flag; int rel;
    if      (i < 8192)  { src = w1; dst = W1p; flag = flags[4]; rel = i; }
    else if (i < 16384) { src = w2; dst = W2p; flag = flags[6]; rel = i - 8192; }
    else return;
    if (flag) {
        dst[rel] = ((const unsigned int*)src)[rel];
    } else {
        const float* s = (const float*)src;
        unsigned int lo = f2bf(s[2 * rel]);
        unsigned int hi = f2bf(s[2 * rel + 1]);
        dst[rel] = lo | (hi << 16);
    }
}

// ---------- graph preprocessing ----------
__global__ __launch_bounds__(256) void deg_kernel(const int* ei, const int* iflag,
                                                  int* deg) {
    int e = blockIdx.x * 256 + threadIdx.x;
    int is64 = *iflag;
    if (e < NE) atomicAdd(&deg[ld_idx(ei, NE + e, is64)], 1);
}
__global__ __launch_bounds__(256) void dinv_kernel(const int* deg, float* dinv) {
    int i = blockIdx.x * 256 + threadIdx.x;
    if (i < NN) dinv[i] = rsqrtf((float)(deg[i] + 1));
}
__global__ __launch_bounds__(1024) void scan_kernel(const int* deg, int* rowstart,
                                                    int* cursor) {
    __shared__ int part[1024];
    const int T = 1024;
    const int chunk = (NN + T - 1) / T;
    int s = threadIdx.x * chunk;
    int e = s + chunk;
    if (e > NN) e = NN;
    if (s > NN) s = NN;
    int sum = 0;
    for (int i = s; i < e; ++i) sum += deg[i] + 1;
    part[threadIdx.x] = sum;
    __syncthreads();
    for (int off = 1; off < T; off <<= 1) {
        int v = part[threadIdx.x];
        int a = ((int)threadIdx.x >= off) ? part[threadIdx.x - off] : 0;
        __syncthreads();
        part[threadIdx.x] = v + a;
        __syncthreads();
    }
    int excl = (threadIdx.x == 0) ? 0 : part[threadIdx.x - 1];
    for (int i = s; i < e; ++i) {
        rowstart[i] = excl;
        cursor[i]   = excl;
        excl += deg[i] + 1;
    }
    if (threadIdx.x == T - 1) rowstart[NN] = excl;
}
__global__ __launch_bounds__(256) void fill_kernel(const int* ei, const int* iflag,
        const float* dinv, int* cursor, int* col, float* val) {
    int e = blockIdx.x * 256 + threadIdx.x;
    if (e >= EETOT) return;
    int is64 = *iflag;
    int s, d;
    if (e < NE) { s = ld_idx(ei, e, is64); d = ld_idx(ei, NE + e, is64); }
    else        { s = d = e - NE; }
    int pos = atomicAdd(&cursor[d], 1);
    col[pos] = s;
    val[pos] = dinv[s] * dinv[d];
}

// ---------- graph-boundary kernel (batch sorted): gstart[NG+1], no atomics ----------
__global__ __launch_bounds__(256) void gstart_kernel(const int* batch, const int* bflag,
                                                     int* gstart) {
    int n = blockIdx.x * 256 + threadIdx.x;
    if (n >= NN) return;
    int is64 = *bflag;
    int bc = ld_idx(batch, n, is64);
    if (n == 0) {
        for (int g = 0; g <= bc; ++g) gstart[g] = 0;
    } else {
        int bp = ld_idx(batch, n - 1, is64);
        for (int g = bp + 1; g <= bc; ++g) gstart[g] = n;
    }
    if (n == NN - 1) {
        for (int g = bc + 1; g <= NG; ++g) gstart[g] = NN;
    }
}

// ---------- GEMMs: JAX layout — W (in,out) row-major, C = A @ W ----------
__global__ __launch_bounds__(256) void gemm1(const void* Ap, const int* xflag,
        const unsigned int* Wp, float* C) {
    __shared__ unsigned int Ws[FD * FD / 2];
    __shared__ float As[8][FD];
    for (int i = threadIdx.x; i < FD * FD / 2; i += 256) Ws[i] = Wp[i];
    int ar = threadIdx.x >> 5;
    int ac = (threadIdx.x & 31) * 4;
    int grow = blockIdx.x * 8 + ar;
    if (grow < NN) {
        if (*xflag) {
            const unsigned int* A = (const unsigned int*)Ap;
            unsigned int w0 = A[((size_t)grow * FD + ac) / 2];
            unsigned int w1 = A[((size_t)grow * FD + ac) / 2 + 1];
            As[ar][ac + 0] = bflo(w0); As[ar][ac + 1] = bfhi(w0);
            As[ar][ac + 2] = bflo(w1); As[ar][ac + 3] = bfhi(w1);
        } else {
            const float* A = (const float*)Ap;
            size_t b = (size_t)grow * FD + ac;
            As[ar][ac + 0] = A[b + 0]; As[ar][ac + 1] = A[b + 1];
            As[ar][ac + 2] = A[b + 2]; As[ar][ac + 3] = A[b + 3];
        }
    }
    __syncthreads();
    float a0 = 0.f, a1 = 0.f, a2 = 0.f, a3 = 0.f;
    #pragma unroll 8
    for (int k = 0; k < FD; ++k) {
        float a = As[ar][k];
        unsigned int w0 = Ws[(k * FD + ac) / 2];
        unsigned int w1 = Ws[(k * FD + ac) / 2 + 1];
        a0 += a * bflo(w0);
        a1 += a * bfhi(w0);
        a2 += a * bflo(w1);
        a3 += a * bfhi(w1);
    }
    if (grow < NN) {
        size_t b = (size_t)grow * FD + ac;
        C[b + 0] = a0; C[b + 1] = a1; C[b + 2] = a2; C[b + 3] = a3;
    }
}
__global__ __launch_bounds__(256) void gemm2(const float* A, const unsigned int* Wp,
                                             float* C) {
    __shared__ unsigned int Ws[FD * FD / 2];
    __shared__ float As[8][FD];
    for (int i = threadIdx.x; i < FD * FD / 2; i += 256) Ws[i] = Wp[i];
    int ar = threadIdx.x >> 5;
    int ac = (threadIdx.x & 31) * 4;
    int grow = blockIdx.x * 8 + ar;
    if (grow < NN) {
        size_t b = (size_t)grow * FD + ac;
        As[ar][ac + 0] = A[b + 0]; As[ar][ac + 1] = A[b + 1];
        As[ar][ac + 2] = A[b + 2]; As[ar][ac + 3] = A[b + 3];
    }
    __syncthreads();
    float a0 = 0.f, a1 = 0.f, a2 = 0.f, a3 = 0.f;
    #pragma unroll 8
    for (int k = 0; k < FD; ++k) {
        float a = As[ar][k];
        unsigned int w0 = Ws[(k * FD + ac) / 2];
        unsigned int w1 = Ws[(k * FD + ac) / 2 + 1];
        a0 += a * bflo(w0);
        a1 += a * bfhi(w0);
        a2 += a * bflo(w1);
        a3 += a * bfhi(w1);
    }
    if (grow < NN) {
        size_t b = (size_t)grow * FD + ac;
        C[b + 0] = a0; C[b + 1] = a1; C[b + 2] = a2; C[b + 3] = a3;
    }
}

// ---------- CSR aggregation + bias + relu ----------
__global__ __launch_bounds__(256) void aggregate_kernel(const float* H, const int* col,
        const float* val, const int* rowstart, const float* bias, float* out) {
    int n = blockIdx.x * 2 + (threadIdx.x >> 7);
    int c = threadIdx.x & 127;
    if (n >= NN) return;
    int jb = rowstart[n], je = rowstart[n + 1];
    float acc = 0.f;
    for (int j = jb; j < je; ++j)
        acc += val[j] * H[(size_t)col[j] * FD + c];
    acc += bias[c];
    out[(size_t)n * FD + c] = fmaxf(acc, 0.f);
}

// ---------- segmented mean-pool: one block per graph, no atomics ----------
__global__ __launch_bounds__(128) void pool_seg(const float* H, const int* gstart,
                                                float* sums) {
    int g = blockIdx.x;
    int c = threadIdx.x;
    int s = gstart[g], e = gstart[g + 1];
    float a0 = 0.f, a1 = 0.f;
    int n = s;
    for (; n + 1 < e; n += 2) {
        a0 += H[(size_t)n * FD + c];
        a1 += H[(size_t)(n + 1) * FD + c];
    }
    if (n < e) a0 += H[(size_t)n * FD + c];
    sums[g * FD + c] = a0 + a1;
}

// ---------- head (cnt from gstart); output fp32 unless inputs bf16 ----------
__global__ __launch_bounds__(128) void head_kernel(const float* sums, const int* gstart,
        const float* addf, const float* fc1w, const float* fc1b,
        const float* fc2w, const float* fc2b, const int* xflag, void* outp) {
    int g = blockIdx.x;
    int t = threadIdx.x;
    __shared__ float z[FD + FA];
    __shared__ float h[FD];
    float cnt = (float)(gstart[g + 1] - gstart[g]);
    if (cnt < 1.0f) cnt = 1.0f;
    z[t] = sums[g * FD + t] / cnt;
    if (t < FA) z[FD + t] = addf[g * FA + t];
    __syncthreads();
    float acc = fc1b[t];
    #pragma unroll 4
    for (int k = 0; k < FD + FA; ++k)
        acc += z[k] * fc1w[k * FD + t];
    h[t] = fmaxf(acc, 0.f);
    __syncthreads();
    if (t < 2) {
        float o = fc2b[t];
        for (int j = 0; j < FD; ++j) o += h[j] * fc2w[j * 2 + t];
        if (*xflag) ((unsigned short*)outp)[g * 2 + t] = f2bf(o);
        else        ((float*)outp)[g * 2 + t] = o;
    }
}

extern "C" void kernel_launch(void* const* d_in, const int* in_sizes, int n_in,
                              void* d_out, int out_size, void* d_ws, size_t ws_size,
                              hipStream_t stream) {
    (void)out_size;

    if (n_in != 12) {
        hipLaunchKernelGGL(mark_kernel, dim3(1), dim3(128), 0, stream,
                           (float*)d_out, 2000.0f);
        return;
    }
    const int exp_sizes[12] = {6400000, 1600000, 50000, 4096, 16384, 128,
                               16384, 128, 20480, 128, 256, 2};
    for (int i = 0; i < 12; ++i) {
        if (in_sizes[i] != exp_sizes[i]) {
            hipLaunchKernelGGL(mark_kernel, dim3(1), dim3(128), 0, stream,
                               (float*)d_out, 3000.0f + 100.0f * i);
            return;
        }
    }

    size_t off = 0;
    char* base = (char*)d_ws;
#define WSALLOC(ptr, type, nbytes) \
    type* ptr = (type*)(base + off); off += (((size_t)(nbytes)) + 255) & ~(size_t)255;
    WSALLOC(bufA,  float, (size_t)NN * FD * 4)
    WSALLOC(bufB,  float, (size_t)NN * FD * 4)
    WSALLOC(dinv,  float, (size_t)NN * 4)
    WSALLOC(degi,  int,   (size_t)NN * 4)
    WSALLOC(rowst, int,   (size_t)(NN + 1) * 4)
    WSALLOC(cursor,int,   (size_t)NN * 4)
    WSALLOC(col,   int,   (size_t)EETOT * 4)
    WSALLOC(val,   float, (size_t)EETOT * 4)
    WSALLOC(sums,  float, (size_t)NG * FD * 4)
    WSALLOC(gstart,int,   (size_t)(NG + 1) * 4)
    WSALLOC(W1p,   unsigned int, (size_t)FD * FD / 2 * 4)
    WSALLOC(W2p,   unsigned int, (size_t)FD * FD / 2 * 4)
    WSALLOC(b1f,   float, FD * 4)
    WSALLOC(b2f,   float, FD * 4)
    WSALLOC(addff, float, (size_t)NG * FA * 4)
    WSALLOC(fc1wf, float, (size_t)(FD + FA) * FD * 4)
    WSALLOC(fc1bf, float, FD * 4)
    WSALLOC(fc2wf, float, FD * 2 * 4)
    WSALLOC(fc2bf, float, 2 * 4)
    WSALLOC(flags, int, 16 * 4)
#undef WSALLOC
    if (ws_size < off) {
        hipLaunchKernelGGL(mark_kernel, dim3(1), dim3(128), 0, stream,
                           (float*)d_out, 1000.0f);
        return;
    }

    const int* ei    = (const int*)d_in[1];
    const int* batch = (const int*)d_in[2];

    hipLaunchKernelGGL(detect_all, dim3(12), dim3(64), 0, stream,
                       (const unsigned int*)d_in[0], ei, batch,
                       (const unsigned int*)d_in[3], (const unsigned int*)d_in[4],
                       (const unsigned int*)d_in[5], (const unsigned int*)d_in[6],
                       (const unsigned int*)d_in[7], (const unsigned int*)d_in[8],
                       (const unsigned int*)d_in[9], (const unsigned int*)d_in[10],
                       (const unsigned int*)d_in[11], (const int*)0, flags);

    hipLaunchKernelGGL(cvt_f32_all, dim3((25218 + 255) / 256), dim3(256), 0, stream,
                       d_in[3], d_in[5], d_in[7], d_in[8], d_in[9], d_in[10], d_in[11],
                       flags, addff, b1f, b2f, fc1wf, fc1bf, fc2wf, fc2bf);
    hipLaunchKernelGGL(cvt_bf_all, dim3(64), dim3(256), 0, stream,
                       d_in[4], d_in[6], flags, W1p, W2p);

    hipLaunchKernelGGL(zero_i32, dim3((NN + 255) / 256), dim3(256), 0, stream, degi, NN);
    hipLaunchKernelGGL(deg_kernel, dim3((NE + 255) / 256), dim3(256), 0, stream,
                       ei, flags + 12, degi);
    hipLaunchKernelGGL(dinv_kernel, dim3((NN + 255) / 256), dim3(256), 0, stream,
                       degi, dinv);
    hipLaunchKernelGGL(scan_kernel, dim3(1), dim3(1024), 0, stream, degi, rowst, cursor);
    hipLaunchKernelGGL(fill_kernel, dim3((EETOT + 255) / 256), dim3(256), 0, stream,
                       ei, flags + 12, dinv, cursor, col, val);
    hipLaunchKernelGGL(gstart_kernel, dim3((NN + 255) / 256), dim3(256), 0, stream,
                       batch, flags + 13, gstart);

    hipLaunchKernelGGL(gemm1, dim3((NN + 7) / 8), dim3(256), 0, stream,
                       d_in[0], flags + 0, W1p, bufA);
    hipLaunchKernelGGL(aggregate_kernel, dim3(NN / 2), dim3(256), 0, stream,
                       bufA, col, val, rowst, b1f, bufB);
    hipLaunchKernelGGL(gemm2, dim3((NN + 7) / 8), dim3(256), 0, stream, bufB, W2p, bufA);
    hipLaunchKernelGGL(aggregate_kernel, dim3(NN / 2), dim3(256), 0, stream,
                       bufA, col, val, rowst, b2f, bufB);

    hipLaunchKernelGGL(pool_seg, dim3(NG), dim3(128), 0, stream, bufB, gstart, sums);
    hipLaunchKernelGGL(head_kernel, dim3(NG), dim3(FD), 0, stream,
                       sums, gstart, addff, fc1wf, fc1bf, fc2wf, fc2bf,
                       flags + 0, d_out);
}

// Round 10
// 563.799 us; speedup vs baseline: 1.8058x; 1.3309x over previous
//
#include <hip/hip_runtime.h>

#define NN 50000
#define NE 800000
#define FD 128
#define FDH 64            // FD/2 packed bf16 pairs
#define FA 32
#define NG 128
#define EETOT (NE + NN)

// ---------- bf16 helpers, pure bit ops ----------
__device__ __forceinline__ float bfbits(unsigned short u) {
    return __uint_as_float(((unsigned int)u) << 16);
}
__device__ __forceinline__ float bflo(unsigned int p) { return __uint_as_float(p << 16); }
__device__ __forceinline__ float bfhi(unsigned int p) { return __uint_as_float(p & 0xffff0000u); }
__device__ __forceinline__ unsigned short f2bf(float f) {   // RNE
    unsigned int u = __float_as_uint(f);
    unsigned int r = u + 0x7FFFu + ((u >> 16) & 1u);
    return (unsigned short)(r >> 16);
}
__device__ __forceinline__ unsigned int packbf(float a, float b) {
    return (unsigned int)f2bf(a) | ((unsigned int)f2bf(b) << 16);
}
__device__ __forceinline__ int ld_idx(const int* p, int i, int is64) {
    return is64 ? p[2 * i] : p[i];
}

// ---------- sentinels ----------
__global__ __launch_bounds__(128) void mark_kernel(float* out, float v) {
    out[threadIdx.x] = v;
}
__global__ __launch_bounds__(256) void zero_i32(int* p, int n) {
    int i = blockIdx.x * 256 + threadIdx.x;
    if (i < n) p[i] = 0;
}

// ---------- all dtype detection in one launch ----------
__global__ __launch_bounds__(64) void detect_all(
        const unsigned int* x, const int* ei, const int* batch,
        const unsigned int* addf, const unsigned int* w1, const unsigned int* b1,
        const unsigned int* w2, const unsigned int* b2, const unsigned int* fc1w,
        const unsigned int* fc1b, const unsigned int* fc2w, const unsigned int* fc2b,
        int* flags) {
    if (threadIdx.x != 0) return;
    int b = blockIdx.x;
    if (b < 10) {
        const unsigned int* t = x; int nw = 64; int idx = 0;
        switch (b) {
            case 0: t = x;    nw = 64; idx = 0;  break;
            case 1: t = addf; nw = 64; idx = 3;  break;
            case 2: t = w1;   nw = 64; idx = 4;  break;
            case 3: t = b1;   nw = 64; idx = 5;  break;
            case 4: t = w2;   nw = 64; idx = 6;  break;
            case 5: t = b2;   nw = 64; idx = 7;  break;
            case 6: t = fc1w; nw = 64; idx = 8;  break;
            case 7: t = fc1b; nw = 64; idx = 9;  break;
            case 8: t = fc2w; nw = 64; idx = 10; break;
            case 9: t = fc2b; nw = 1;  idx = 11; break;
        }
        int nz = 0, hits = 0;
        for (int i = 0; i < nw; ++i) {
            unsigned int w = t[i];
            if (w == 0u) continue;
            ++nz;
            unsigned int e = (w >> 7) & 0xFFu;
            if (e >= 100u && e <= 140u) ++hits;
        }
        flags[idx] = (nz < 8) ? 1 : (hits * 4 >= nz * 3);
    } else if (b == 10) {
        int odd_or = 0;
        for (int k = 0; k < 32; ++k) odd_or |= ei[2 * k + 1];
        flags[12] = (odd_or == 0) ? 1 : 0;
    } else {
        flags[13] = (batch[NN - 1] == 0) ? 1 : 0;   // sorted: tail nonzero iff int32
        flags[14] = 1;                               // constant "bf16" flag for layer-2 A
    }
}

// ---------- canonicalize fp32-destination weights (one launch) ----------
__global__ __launch_bounds__(256) void cvt_f32_all(
        const void* addf, const void* b1, const void* b2, const void* fc1w,
        const void* fc1b, const void* fc2w, const void* fc2b, const int* flags,
        float* addff, float* b1f, float* b2f, float* fc1wf,
        float* fc1bf, float* fc2wf, float* fc2bf) {
    int i = blockIdx.x * 256 + threadIdx.x;
    const void* src; float* dst; int flag; int rel;
    if      (i < 4096)  { src = addf; dst = addff; flag = flags[3];  rel = i; }
    else if (i < 4224)  { src = b1;   dst = b1f;   flag = flags[5];  rel = i - 4096; }
    else if (i < 4352)  { src = b2;   dst = b2f;   flag = flags[7];  rel = i - 4224; }
    else if (i < 24832) { src = fc1w; dst = fc1wf; flag = flags[8];  rel = i - 4352; }
    else if (i < 24960) { src = fc1b; dst = fc1bf; flag = flags[9];  rel = i - 24832; }
    else if (i < 25216) { src = fc2w; dst = fc2wf; flag = flags[10]; rel = i - 24960; }
    else if (i < 25218) { src = fc2b; dst = fc2bf; flag = flags[11]; rel = i - 25216; }
    else return;
    if (flag) dst[rel] = bfbits(((const unsigned short*)src)[rel]);
    else      dst[rel] = ((const float*)src)[rel];
}

// ---------- canonicalize W1/W2 to packed bf16 (one launch) ----------
__global__ __launch_bounds__(256) void cvt_bf_all(const void* w1, const void* w2,
        const int* flags, unsigned int* W1p, unsigned int* W2p) {
    int i = blockIdx.x * 256 + threadIdx.x;
    const void* src; unsigned int* dst; int flag; int rel;
    if      (i < 8192)  { src = w1; dst = W1p; flag = flags[4]; rel = i; }
    else if (i < 16384) { src = w2; dst = W2p; flag = flags[6]; rel = i - 8192; }
    else return;
    if (flag) {
        dst[rel] = ((const unsigned int*)src)[rel];
    } else {
        const float* s = (const float*)src;
        dst[rel] = packbf(s[2 * rel], s[2 * rel + 1]);
    }
}

// ---------- graph preprocessing ----------
__global__ __launch_bounds__(256) void deg_kernel(const int* ei, const int* iflag,
                                                  int* deg) {
    int e = blockIdx.x * 256 + threadIdx.x;
    int is64 = *iflag;
    if (e < NE) atomicAdd(&deg[ld_idx(ei, NE + e, is64)], 1);
}
__global__ __launch_bounds__(256) void dinv_kernel(const int* deg, float* dinv) {
    int i = blockIdx.x * 256 + threadIdx.x;
    if (i < NN) dinv[i] = rsqrtf((float)(deg[i] + 1));
}
__global__ __launch_bounds__(1024) void scan_kernel(const int* deg, int* rowstart,
                                                    int* cursor) {
    __shared__ int part[1024];
    const int T = 1024;
    const int chunk = (NN + T - 1) / T;
    int s = threadIdx.x * chunk;
    int e = s + chunk;
    if (e > NN) e = NN;
    if (s > NN) s = NN;
    int sum = 0;
    for (int i = s; i < e; ++i) sum += deg[i] + 1;
    part[threadIdx.x] = sum;
    __syncthreads();
    for (int off = 1; off < T; off <<= 1) {
        int v = part[threadIdx.x];
        int a = ((int)threadIdx.x >= off) ? part[threadIdx.x - off] : 0;
        __syncthreads();
        part[threadIdx.x] = v + a;
        __syncthreads();
    }
    int excl = (threadIdx.x == 0) ? 0 : part[threadIdx.x - 1];
    for (int i = s; i < e; ++i) {
        rowstart[i] = excl;
        cursor[i]   = excl;
        excl += deg[i] + 1;
    }
    if (threadIdx.x == T - 1) rowstart[NN] = excl;
}
// cv[pos] = {src, bits(norm)} — single 8B record per edge
__global__ __launch_bounds__(256) void fill_kernel(const int* ei, const int* iflag,
        const float* dinv, int* cursor, int2* cv) {
    int e = blockIdx.x * 256 + threadIdx.x;
    if (e >= EETOT) return;
    int is64 = *iflag;
    int s, d;
    if (e < NE) { s = ld_idx(ei, e, is64); d = ld_idx(ei, NE + e, is64); }
    else        { s = d = e - NE; }
    int pos = atomicAdd(&cursor[d], 1);
    cv[pos] = make_int2(s, __float_as_int(dinv[s] * dinv[d]));
}

// ---------- graph boundaries (batch sorted) ----------
__global__ __launch_bounds__(256) void gstart_kernel(const int* batch, const int* bflag,
                                                     int* gstart) {
    int n = blockIdx.x * 256 + threadIdx.x;
    if (n >= NN) return;
    int is64 = *bflag;
    int bc = ld_idx(batch, n, is64);
    if (n == 0) {
        for (int g = 0; g <= bc; ++g) gstart[g] = 0;
    } else {
        int bp = ld_idx(batch, n - 1, is64);
        for (int g = bp + 1; g <= bc; ++g) gstart[g] = n;
    }
    if (n == NN - 1) {
        for (int g = bc + 1; g <= NG; ++g) gstart[g] = NN;
    }
}

// ---------- GEMM: A (fp32 or packed bf16 via aflag), W packed bf16, C packed bf16 ----------
__global__ __launch_bounds__(256) void gemm(const void* Ap, const int* aflag,
        const unsigned int* Wp, unsigned int* Cb) {
    __shared__ unsigned int Ws[FD * FDH];
    __shared__ float As[8][FD];
    for (int i = threadIdx.x; i < FD * FDH; i += 256) Ws[i] = Wp[i];
    int ar = threadIdx.x >> 5;
    int ac = (threadIdx.x & 31) * 4;
    int grow = blockIdx.x * 8 + ar;
    if (grow < NN) {
        if (*aflag) {
            const unsigned int* A = (const unsigned int*)Ap;
            unsigned int w0 = A[(size_t)grow * FDH + (ac >> 1)];
            unsigned int w1 = A[(size_t)grow * FDH + (ac >> 1) + 1];
            As[ar][ac + 0] = bflo(w0); As[ar][ac + 1] = bfhi(w0);
            As[ar][ac + 2] = bflo(w1); As[ar][ac + 3] = bfhi(w1);
        } else {
            const float* A = (const float*)Ap;
            size_t b = (size_t)grow * FD + ac;
            As[ar][ac + 0] = A[b + 0]; As[ar][ac + 1] = A[b + 1];
            As[ar][ac + 2] = A[b + 2]; As[ar][ac + 3] = A[b + 3];
        }
    }
    __syncthreads();
    float a0 = 0.f, a1 = 0.f, a2 = 0.f, a3 = 0.f;
    #pragma unroll 8
    for (int k = 0; k < FD; ++k) {
        float a = As[ar][k];
        unsigned int w0 = Ws[k * FDH + (ac >> 1)];
        unsigned int w1 = Ws[k * FDH + (ac >> 1) + 1];
        a0 += a * bflo(w0);
        a1 += a * bfhi(w0);
        a2 += a * bflo(w1);
        a3 += a * bfhi(w1);
    }
    if (grow < NN) {
        Cb[(size_t)grow * FDH + (ac >> 1)]     = packbf(a0, a1);
        Cb[(size_t)grow * FDH + (ac >> 1) + 1] = packbf(a2, a3);
    }
}

// ---------- CSR aggregation (bf16 gather) + bias + relu -> bf16 ----------
// 4 nodes per 256-thread block; one wave per node; lane = channel pair
__global__ __launch_bounds__(256) void aggregate_kernel(const unsigned int* Hb,
        const int2* cv, const int* rowstart, const float* bias, unsigned int* outb) {
    int n = blockIdx.x * 4 + (threadIdx.x >> 6);
    int cp = threadIdx.x & 63;
    if (n >= NN) return;
    int jb = rowstart[n], je = rowstart[n + 1];
    float acc0 = 0.f, acc1 = 0.f;
    int j = jb;
    for (; j + 1 < je; j += 2) {
        int2 e0 = cv[j], e1 = cv[j + 1];
        unsigned int h0 = Hb[(size_t)e0.x * FDH + cp];
        unsigned int h1 = Hb[(size_t)e1.x * FDH + cp];
        float v0 = __int_as_float(e0.y), v1 = __int_as_float(e1.y);
        acc0 += v0 * bflo(h0) + v1 * bflo(h1);
        acc1 += v0 * bfhi(h0) + v1 * bfhi(h1);
    }
    if (j < je) {
        int2 e0 = cv[j];
        unsigned int h0 = Hb[(size_t)e0.x * FDH + cp];
        float v0 = __int_as_float(e0.y);
        acc0 += v0 * bflo(h0);
        acc1 += v0 * bfhi(h0);
    }
    acc0 = fmaxf(acc0 + bias[2 * cp], 0.f);
    acc1 = fmaxf(acc1 + bias[2 * cp + 1], 0.f);
    outb[(size_t)n * FDH + cp] = packbf(acc0, acc1);
}

// ---------- segmented mean-pool over bf16 H ----------
__global__ __launch_bounds__(64) void pool_seg(const unsigned int* Hb, const int* gstart,
                                               float* sums) {
    int g = blockIdx.x;
    int cp = threadIdx.x;
    int s = gstart[g], e = gstart[g + 1];
    float a0 = 0.f, a1 = 0.f, b0 = 0.f, b1 = 0.f;
    int n = s;
    for (; n + 1 < e; n += 2) {
        unsigned int h0 = Hb[(size_t)n * FDH + cp];
        unsigned int h1 = Hb[(size_t)(n + 1) * FDH + cp];
        a0 += bflo(h0); a1 += bfhi(h0);
        b0 += bflo(h1); b1 += bfhi(h1);
    }
    if (n < e) {
        unsigned int h0 = Hb[(size_t)n * FDH + cp];
        a0 += bflo(h0); a1 += bfhi(h0);
    }
    sums[g * FD + 2 * cp]     = a0 + b0;
    sums[g * FD + 2 * cp + 1] = a1 + b1;
}

// ---------- head ----------
__global__ __launch_bounds__(128) void head_kernel(const float* sums, const int* gstart,
        const float* addf, const float* fc1w, const float* fc1b,
        const float* fc2w, const float* fc2b, const int* xflag, void* outp) {
    int g = blockIdx.x;
    int t = threadIdx.x;
    __shared__ float z[FD + FA];
    __shared__ float h[FD];
    float cnt = (float)(gstart[g + 1] - gstart[g]);
    if (cnt < 1.0f) cnt = 1.0f;
    z[t] = sums[g * FD + t] / cnt;
    if (t < FA) z[FD + t] = addf[g * FA + t];
    __syncthreads();
    float acc = fc1b[t];
    #pragma unroll 4
    for (int k = 0; k < FD + FA; ++k)
        acc += z[k] * fc1w[k * FD + t];
    h[t] = fmaxf(acc, 0.f);
    __syncthreads();
    if (t < 2) {
        float o = fc2b[t];
        for (int j = 0; j < FD; ++j) o += h[j] * fc2w[j * 2 + t];
        if (*xflag) ((unsigned short*)outp)[g * 2 + t] = f2bf(o);
        else        ((float*)outp)[g * 2 + t] = o;
    }
}

extern "C" void kernel_launch(void* const* d_in, const int* in_sizes, int n_in,
                              void* d_out, int out_size, void* d_ws, size_t ws_size,
                              hipStream_t stream) {
    (void)out_size;

    if (n_in != 12) {
        hipLaunchKernelGGL(mark_kernel, dim3(1), dim3(128), 0, stream,
                           (float*)d_out, 2000.0f);
        return;
    }
    const int exp_sizes[12] = {6400000, 1600000, 50000, 4096, 16384, 128,
                               16384, 128, 20480, 128, 256, 2};
    for (int i = 0; i < 12; ++i) {
        if (in_sizes[i] != exp_sizes[i]) {
            hipLaunchKernelGGL(mark_kernel, dim3(1), dim3(128), 0, stream,
                               (float*)d_out, 3000.0f + 100.0f * i);
            return;
        }
    }

    size_t off = 0;
    char* base = (char*)d_ws;
#define WSALLOC(ptr, type, nbytes) \
    type* ptr = (type*)(base + off); off += (((size_t)(nbytes)) + 255) & ~(size_t)255;
    WSALLOC(bufA,  unsigned int, (size_t)NN * FDH * 4)   // packed bf16 H
    WSALLOC(bufB,  unsigned int, (size_t)NN * FDH * 4)
    WSALLOC(dinv,  float, (size_t)NN * 4)
    WSALLOC(degi,  int,   (size_t)NN * 4)
    WSALLOC(rowst, int,   (size_t)(NN + 1) * 4)
    WSALLOC(cursor,int,   (size_t)NN * 4)
    WSALLOC(cv,    int2,  (size_t)EETOT * 8)
    WSALLOC(sums,  float, (size_t)NG * FD * 4)
    WSALLOC(gstart,int,   (size_t)(NG + 1) * 4)
    WSALLOC(W1p,   unsigned int, (size_t)FD * FDH * 4)
    WSALLOC(W2p,   unsigned int, (size_t)FD * FDH * 4)
    WSALLOC(b1f,   float, FD * 4)
    WSALLOC(b2f,   float, FD * 4)
    WSALLOC(addff, float, (size_t)NG * FA * 4)
    WSALLOC(fc1wf, float, (size_t)(FD + FA) * FD * 4)
    WSALLOC(fc1bf, float, FD * 4)
    WSALLOC(fc2wf, float, FD * 2 * 4)
    WSALLOC(fc2bf, float, 2 * 4)
    WSALLOC(flags, int, 16 * 4)
#undef WSALLOC
    if (ws_size < off) {
        hipLaunchKernelGGL(mark_kernel, dim3(1), dim3(128), 0, stream,
                           (float*)d_out, 1000.0f);
        return;
    }

    const int* ei    = (const int*)d_in[1];
    const int* batch = (const int*)d_in[2];

    hipLaunchKernelGGL(detect_all, dim3(12), dim3(64), 0, stream,
                       (const unsigned int*)d_in[0], ei, batch,
                       (const unsigned int*)d_in[3], (const unsigned int*)d_in[4],
                       (const unsigned int*)d_in[5], (const unsigned int*)d_in[6],
                       (const unsigned int*)d_in[7], (const unsigned int*)d_in[8],
                       (const unsigned int*)d_in[9], (const unsigned int*)d_in[10],
                       (const unsigned int*)d_in[11], flags);

    hipLaunchKernelGGL(cvt_f32_all, dim3((25218 + 255) / 256), dim3(256), 0, stream,
                       d_in[3], d_in[5], d_in[7], d_in[8], d_in[9], d_in[10], d_in[11],
                       flags, addff, b1f, b2f, fc1wf, fc1bf, fc2wf, fc2bf);
    hipLaunchKernelGGL(cvt_bf_all, dim3(64), dim3(256), 0, stream,
                       d_in[4], d_in[6], flags, W1p, W2p);

    hipLaunchKernelGGL(zero_i32, dim3((NN + 255) / 256), dim3(256), 0, stream, degi, NN);
    hipLaunchKernelGGL(deg_kernel, dim3((NE + 255) / 256), dim3(256), 0, stream,
                       ei, flags + 12, degi);
    hipLaunchKernelGGL(dinv_kernel, dim3((NN + 255) / 256), dim3(256), 0, stream,
                       degi, dinv);
    hipLaunchKernelGGL(scan_kernel, dim3(1), dim3(1024), 0, stream, degi, rowst, cursor);
    hipLaunchKernelGGL(fill_kernel, dim3((EETOT + 255) / 256), dim3(256), 0, stream,
                       ei, flags + 12, dinv, cursor, cv);
    hipLaunchKernelGGL(gstart_kernel, dim3((NN + 255) / 256), dim3(256), 0, stream,
                       batch, flags + 13, gstart);

    hipLaunchKernelGGL(gemm, dim3((NN + 7) / 8), dim3(256), 0, stream,
                       d_in[0], flags + 0, W1p, bufA);
    hipLaunchKernelGGL(aggregate_kernel, dim3((NN + 3) / 4), dim3(256), 0, stream,
                       bufA, cv, rowst, b1f, bufB);
    hipLaunchKernelGGL(gemm, dim3((NN + 7) / 8), dim3(256), 0, stream,
                       bufB, flags + 14, W2p, bufA);
    hipLaunchKernelGGL(aggregate_kernel, dim3((NN + 3) / 4), dim3(256), 0, stream,
                       bufA, cv, rowst, b2f, bufB);

    hipLaunchKernelGGL(pool_seg, dim3(NG), dim3(64), 0, stream, bufB, gstart, sums);
    hipLaunchKernelGGL(head_kernel, dim3(NG), dim3(FD), 0, stream,
                       sums, gstart, addff, fc1wf, fc1bf, fc2wf, fc2bf,
                       flags + 0, d_out);
}

// Round 11
// 457.844 us; speedup vs baseline: 2.2237x; 1.2314x over previous
//
#include <hip/hip_runtime.h>

#define NN 50000
#define NE 800000
#define FD 128
#define FDH 64            // FD/2 packed bf16 pairs
#define FA 32
#define NG 128
#define EETOT (NE + NN)
#define NBLK ((NN + 255) / 256)   // 196 scan blocks

// ---------- bf16 helpers, pure bit ops ----------
__device__ __forceinline__ float bfbits(unsigned short u) {
    return __uint_as_float(((unsigned int)u) << 16);
}
__device__ __forceinline__ float bflo(unsigned int p) { return __uint_as_float(p << 16); }
__device__ __forceinline__ float bfhi(unsigned int p) { return __uint_as_float(p & 0xffff0000u); }
__device__ __forceinline__ unsigned short f2bf(float f) {   // RNE
    unsigned int u = __float_as_uint(f);
    unsigned int r = u + 0x7FFFu + ((u >> 16) & 1u);
    return (unsigned short)(r >> 16);
}
__device__ __forceinline__ unsigned int packbf(float a, float b) {
    return (unsigned int)f2bf(a) | ((unsigned int)f2bf(b) << 16);
}
__device__ __forceinline__ int ld_idx(const int* p, int i, int is64) {
    return is64 ? p[2 * i] : p[i];
}

// ---------- sentinels ----------
__global__ __launch_bounds__(128) void mark_kernel(float* out, float v) {
    out[threadIdx.x] = v;
}
__global__ __launch_bounds__(256) void zero_i32(int* p, int n) {
    int i = blockIdx.x * 256 + threadIdx.x;
    if (i < n) p[i] = 0;
}

// ---------- all dtype detection in one launch ----------
__global__ __launch_bounds__(64) void detect_all(
        const unsigned int* x, const int* ei, const int* batch,
        const unsigned int* addf, const unsigned int* w1, const unsigned int* b1,
        const unsigned int* w2, const unsigned int* b2, const unsigned int* fc1w,
        const unsigned int* fc1b, const unsigned int* fc2w, const unsigned int* fc2b,
        int* flags) {
    if (threadIdx.x != 0) return;
    int b = blockIdx.x;
    if (b < 10) {
        const unsigned int* t = x; int nw = 64; int idx = 0;
        switch (b) {
            case 0: t = x;    nw = 64; idx = 0;  break;
            case 1: t = addf; nw = 64; idx = 3;  break;
            case 2: t = w1;   nw = 64; idx = 4;  break;
            case 3: t = b1;   nw = 64; idx = 5;  break;
            case 4: t = w2;   nw = 64; idx = 6;  break;
            case 5: t = b2;   nw = 64; idx = 7;  break;
            case 6: t = fc1w; nw = 64; idx = 8;  break;
            case 7: t = fc1b; nw = 64; idx = 9;  break;
            case 8: t = fc2w; nw = 64; idx = 10; break;
            case 9: t = fc2b; nw = 1;  idx = 11; break;
        }
        int nz = 0, hits = 0;
        for (int i = 0; i < nw; ++i) {
            unsigned int w = t[i];
            if (w == 0u) continue;
            ++nz;
            unsigned int e = (w >> 7) & 0xFFu;
            if (e >= 100u && e <= 140u) ++hits;
        }
        flags[idx] = (nz < 8) ? 1 : (hits * 4 >= nz * 3);
    } else if (b == 10) {
        int odd_or = 0;
        for (int k = 0; k < 32; ++k) odd_or |= ei[2 * k + 1];
        flags[12] = (odd_or == 0) ? 1 : 0;
    } else {
        flags[13] = (batch[NN - 1] == 0) ? 1 : 0;   // sorted: tail nonzero iff int32
        flags[14] = 1;                               // constant "bf16" flag for layer-2 A
    }
}

// ---------- canonicalize fp32-destination weights (one launch) ----------
__global__ __launch_bounds__(256) void cvt_f32_all(
        const void* addf, const void* b1, const void* b2, const void* fc1w,
        const void* fc1b, const void* fc2w, const void* fc2b, const int* flags,
        float* addff, float* b1f, float* b2f, float* fc1wf,
        float* fc1bf, float* fc2wf, float* fc2bf) {
    int i = blockIdx.x * 256 + threadIdx.x;
    const void* src; float* dst; int flag; int rel;
    if      (i < 4096)  { src = addf; dst = addff; flag = flags[3];  rel = i; }
    else if (i < 4224)  { src = b1;   dst = b1f;   flag = flags[5];  rel = i - 4096; }
    else if (i < 4352)  { src = b2;   dst = b2f;   flag = flags[7];  rel = i - 4224; }
    else if (i < 24832) { src = fc1w; dst = fc1wf; flag = flags[8];  rel = i - 4352; }
    else if (i < 24960) { src = fc1b; dst = fc1bf; flag = flags[9];  rel = i - 24832; }
    else if (i < 25216) { src = fc2w; dst = fc2wf; flag = flags[10]; rel = i - 24960; }
    else if (i < 25218) { src = fc2b; dst = fc2bf; flag = flags[11]; rel = i - 25216; }
    else return;
    if (flag) dst[rel] = bfbits(((const unsigned short*)src)[rel]);
    else      dst[rel] = ((const float*)src)[rel];
}

// ---------- canonicalize W1/W2 to packed bf16 (one launch) ----------
__global__ __launch_bounds__(256) void cvt_bf_all(const void* w1, const void* w2,
        const int* flags, unsigned int* W1p, unsigned int* W2p) {
    int i = blockIdx.x * 256 + threadIdx.x;
    const void* src; unsigned int* dst; int flag; int rel;
    if      (i < 8192)  { src = w1; dst = W1p; flag = flags[4]; rel = i; }
    else if (i < 16384) { src = w2; dst = W2p; flag = flags[6]; rel = i - 8192; }
    else return;
    if (flag) {
        dst[rel] = ((const unsigned int*)src)[rel];
    } else {
        const float* s = (const float*)src;
        dst[rel] = packbf(s[2 * rel], s[2 * rel + 1]);
    }
}

// ---------- graph preprocessing ----------
__global__ __launch_bounds__(256) void deg_kernel(const int* ei, const int* iflag,
                                                  int* deg) {
    int e = blockIdx.x * 256 + threadIdx.x;
    int is64 = *iflag;
    if (e < NE) atomicAdd(&deg[ld_idx(ei, NE + e, is64)], 1);
}
__global__ __launch_bounds__(256) void dinv_kernel(const int* deg, float* dinv) {
    int i = blockIdx.x * 256 + threadIdx.x;
    if (i < NN) dinv[i] = rsqrtf((float)(deg[i] + 1));
}

// ---------- device-wide exclusive scan of (deg[i]+1), 3 phases ----------
__global__ __launch_bounds__(256) void scan1(const int* deg, int* escan, int* bsum) {
    __shared__ int sh[256];
    int i = blockIdx.x * 256 + threadIdx.x;
    int v = (i < NN) ? deg[i] + 1 : 0;
    sh[threadIdx.x] = v;
    __syncthreads();
    for (int off = 1; off < 256; off <<= 1) {
        int a = ((int)threadIdx.x >= off) ? sh[threadIdx.x - off] : 0;
        __syncthreads();
        sh[threadIdx.x] += a;
        __syncthreads();
    }
    if (i < NN) escan[i] = sh[threadIdx.x] - v;
    if (threadIdx.x == 255) bsum[blockIdx.x] = sh[255];
}
__global__ __launch_bounds__(256) void scan2(const int* bsum, int* boff) {
    __shared__ int sh[256];
    int t = threadIdx.x;
    int v = (t < NBLK) ? bsum[t] : 0;
    sh[t] = v;
    __syncthreads();
    for (int off = 1; off < 256; off <<= 1) {
        int a = (t >= off) ? sh[t - off] : 0;
        __syncthreads();
        sh[t] += a;
        __syncthreads();
    }
    if (t < NBLK) boff[t] = sh[t] - v;
}
__global__ __launch_bounds__(256) void scan3(const int* escan, const int* boff,
                                             int* rowstart, int* cursor) {
    int i = blockIdx.x * 256 + threadIdx.x;
    if (i < NN) {
        int r = escan[i] + boff[blockIdx.x];
        rowstart[i] = r;
        cursor[i]   = r;
    }
    if (i == 0) rowstart[NN] = EETOT;   // grand total is a compile-time constant
}

// cv[pos] = {src, bits(norm)} — single 8B record per edge
__global__ __launch_bounds__(256) void fill_kernel(const int* ei, const int* iflag,
        const float* dinv, int* cursor, int2* cv) {
    int e = blockIdx.x * 256 + threadIdx.x;
    if (e >= EETOT) return;
    int is64 = *iflag;
    int s, d;
    if (e < NE) { s = ld_idx(ei, e, is64); d = ld_idx(ei, NE + e, is64); }
    else        { s = d = e - NE; }
    int pos = atomicAdd(&cursor[d], 1);
    cv[pos] = make_int2(s, __float_as_int(dinv[s] * dinv[d]));
}

// ---------- graph boundaries (batch sorted) ----------
__global__ __launch_bounds__(256) void gstart_kernel(const int* batch, const int* bflag,
                                                     int* gstart) {
    int n = blockIdx.x * 256 + threadIdx.x;
    if (n >= NN) return;
    int is64 = *bflag;
    int bc = ld_idx(batch, n, is64);
    if (n == 0) {
        for (int g = 0; g <= bc; ++g) gstart[g] = 0;
    } else {
        int bp = ld_idx(batch, n - 1, is64);
        for (int g = bp + 1; g <= bc; ++g) gstart[g] = n;
    }
    if (n == NN - 1) {
        for (int g = bc + 1; g <= NG; ++g) gstart[g] = NN;
    }
}

// ---------- GEMM: A (fp32 or packed bf16 via aflag), W packed bf16, C packed bf16 ----------
__global__ __launch_bounds__(256) void gemm(const void* Ap, const int* aflag,
        const unsigned int* Wp, unsigned int* Cb) {
    __shared__ unsigned int Ws[FD * FDH];
    __shared__ float As[8][FD];
    for (int i = threadIdx.x; i < FD * FDH; i += 256) Ws[i] = Wp[i];
    int ar = threadIdx.x >> 5;
    int ac = (threadIdx.x & 31) * 4;
    int grow = blockIdx.x * 8 + ar;
    if (grow < NN) {
        if (*aflag) {
            const unsigned int* A = (const unsigned int*)Ap;
            unsigned int w0 = A[(size_t)grow * FDH + (ac >> 1)];
            unsigned int w1 = A[(size_t)grow * FDH + (ac >> 1) + 1];
            As[ar][ac + 0] = bflo(w0); As[ar][ac + 1] = bfhi(w0);
            As[ar][ac + 2] = bflo(w1); As[ar][ac + 3] = bfhi(w1);
        } else {
            const float* A = (const float*)Ap;
            size_t b = (size_t)grow * FD + ac;
            As[ar][ac + 0] = A[b + 0]; As[ar][ac + 1] = A[b + 1];
            As[ar][ac + 2] = A[b + 2]; As[ar][ac + 3] = A[b + 3];
        }
    }
    __syncthreads();
    float a0 = 0.f, a1 = 0.f, a2 = 0.f, a3 = 0.f;
    #pragma unroll 8
    for (int k = 0; k < FD; ++k) {
        float a = As[ar][k];
        unsigned int w0 = Ws[k * FDH + (ac >> 1)];
        unsigned int w1 = Ws[k * FDH + (ac >> 1) + 1];
        a0 += a * bflo(w0);
        a1 += a * bfhi(w0);
        a2 += a * bflo(w1);
        a3 += a * bfhi(w1);
    }
    if (grow < NN) {
        Cb[(size_t)grow * FDH + (ac >> 1)]     = packbf(a0, a1);
        Cb[(size_t)grow * FDH + (ac >> 1) + 1] = packbf(a2, a3);
    }
}

// ---------- CSR aggregation (bf16 gather) + bias + relu -> bf16 ----------
__global__ __launch_bounds__(256) void aggregate_kernel(const unsigned int* Hb,
        const int2* cv, const int* rowstart, const float* bias, unsigned int* outb) {
    int n = blockIdx.x * 4 + (threadIdx.x >> 6);
    int cp = threadIdx.x & 63;
    if (n >= NN) return;
    int jb = rowstart[n], je = rowstart[n + 1];
    float acc0 = 0.f, acc1 = 0.f;
    int j = jb;
    for (; j + 1 < je; j += 2) {
        int2 e0 = cv[j], e1 = cv[j + 1];
        unsigned int h0 = Hb[(size_t)e0.x * FDH + cp];
        unsigned int h1 = Hb[(size_t)e1.x * FDH + cp];
        float v0 = __int_as_float(e0.y), v1 = __int_as_float(e1.y);
        acc0 += v0 * bflo(h0) + v1 * bflo(h1);
        acc1 += v0 * bfhi(h0) + v1 * bfhi(h1);
    }
    if (j < je) {
        int2 e0 = cv[j];
        unsigned int h0 = Hb[(size_t)e0.x * FDH + cp];
        float v0 = __int_as_float(e0.y);
        acc0 += v0 * bflo(h0);
        acc1 += v0 * bfhi(h0);
    }
    acc0 = fmaxf(acc0 + bias[2 * cp], 0.f);
    acc1 = fmaxf(acc1 + bias[2 * cp + 1], 0.f);
    outb[(size_t)n * FDH + cp] = packbf(acc0, acc1);
}

// ---------- segmented mean-pool over bf16 H ----------
__global__ __launch_bounds__(64) void pool_seg(const unsigned int* Hb, const int* gstart,
                                               float* sums) {
    int g = blockIdx.x;
    int cp = threadIdx.x;
    int s = gstart[g], e = gstart[g + 1];
    float a0 = 0.f, a1 = 0.f, b0 = 0.f, b1 = 0.f;
    int n = s;
    for (; n + 1 < e; n += 2) {
        unsigned int h0 = Hb[(size_t)n * FDH + cp];
        unsigned int h1 = Hb[(size_t)(n + 1) * FDH + cp];
        a0 += bflo(h0); a1 += bfhi(h0);
        b0 += bflo(h1); b1 += bfhi(h1);
    }
    if (n < e) {
        unsigned int h0 = Hb[(size_t)n * FDH + cp];
        a0 += bflo(h0); a1 += bfhi(h0);
    }
    sums[g * FD + 2 * cp]     = a0 + b0;
    sums[g * FD + 2 * cp + 1] = a1 + b1;
}

// ---------- head ----------
__global__ __launch_bounds__(128) void head_kernel(const float* sums, const int* gstart,
        const float* addf, const float* fc1w, const float* fc1b,
        const float* fc2w, const float* fc2b, const int* xflag, void* outp) {
    int g = blockIdx.x;
    int t = threadIdx.x;
    __shared__ float z[FD + FA];
    __shared__ float h[FD];
    float cnt = (float)(gstart[g + 1] - gstart[g]);
    if (cnt < 1.0f) cnt = 1.0f;
    z[t] = sums[g * FD + t] / cnt;
    if (t < FA) z[FD + t] = addf[g * FA + t];
    __syncthreads();
    float acc = fc1b[t];
    #pragma unroll 4
    for (int k = 0; k < FD + FA; ++k)
        acc += z[k] * fc1w[k * FD + t];
    h[t] = fmaxf(acc, 0.f);
    __syncthreads();
    if (t < 2) {
        float o = fc2b[t];
        for (int j = 0; j < FD; ++j) o += h[j] * fc2w[j * 2 + t];
        if (*xflag) ((unsigned short*)outp)[g * 2 + t] = f2bf(o);
        else        ((float*)outp)[g * 2 + t] = o;
    }
}

extern "C" void kernel_launch(void* const* d_in, const int* in_sizes, int n_in,
                              void* d_out, int out_size, void* d_ws, size_t ws_size,
                              hipStream_t stream) {
    (void)out_size;

    if (n_in != 12) {
        hipLaunchKernelGGL(mark_kernel, dim3(1), dim3(128), 0, stream,
                           (float*)d_out, 2000.0f);
        return;
    }
    const int exp_sizes[12] = {6400000, 1600000, 50000, 4096, 16384, 128,
                               16384, 128, 20480, 128, 256, 2};
    for (int i = 0; i < 12; ++i) {
        if (in_sizes[i] != exp_sizes[i]) {
            hipLaunchKernelGGL(mark_kernel, dim3(1), dim3(128), 0, stream,
                               (float*)d_out, 3000.0f + 100.0f * i);
            return;
        }
    }

    size_t off = 0;
    char* base = (char*)d_ws;
#define WSALLOC(ptr, type, nbytes) \
    type* ptr = (type*)(base + off); off += (((size_t)(nbytes)) + 255) & ~(size_t)255;
    WSALLOC(bufA,  unsigned int, (size_t)NN * FDH * 4)   // packed bf16 H
    WSALLOC(bufB,  unsigned int, (size_t)NN * FDH * 4)
    WSALLOC(dinv,  float, (size_t)NN * 4)
    WSALLOC(degi,  int,   (size_t)NN * 4)
    WSALLOC(rowst, int,   (size_t)(NN + 1) * 4)
    WSALLOC(cursor,int,   (size_t)NN * 4)
    WSALLOC(escan, int,   (size_t)NN * 4)
    WSALLOC(bsum,  int,   (size_t)NBLK * 4)
    WSALLOC(boff,  int,   (size_t)NBLK * 4)
    WSALLOC(cv,    int2,  (size_t)EETOT * 8)
    WSALLOC(sums,  float, (size_t)NG * FD * 4)
    WSALLOC(gstart,int,   (size_t)(NG + 1) * 4)
    WSALLOC(W1p,   unsigned int, (size_t)FD * FDH * 4)
    WSALLOC(W2p,   unsigned int, (size_t)FD * FDH * 4)
    WSALLOC(b1f,   float, FD * 4)
    WSALLOC(b2f,   float, FD * 4)
    WSALLOC(addff, float, (size_t)NG * FA * 4)
    WSALLOC(fc1wf, float, (size_t)(FD + FA) * FD * 4)
    WSALLOC(fc1bf, float, FD * 4)
    WSALLOC(fc2wf, float, FD * 2 * 4)
    WSALLOC(fc2bf, float, 2 * 4)
    WSALLOC(flags, int, 16 * 4)
#undef WSALLOC
    if (ws_size < off) {
        hipLaunchKernelGGL(mark_kernel, dim3(1), dim3(128), 0, stream,
                           (float*)d_out, 1000.0f);
        return;
    }

    const int* ei    = (const int*)d_in[1];
    const int* batch = (const int*)d_in[2];

    hipLaunchKernelGGL(detect_all, dim3(12), dim3(64), 0, stream,
                       (const unsigned int*)d_in[0], ei, batch,
                       (const unsigned int*)d_in[3], (const unsigned int*)d_in[4],
                       (const unsigned int*)d_in[5], (const unsigned int*)d_in[6],
                       (const unsigned int*)d_in[7], (const unsigned int*)d_in[8],
                       (const unsigned int*)d_in[9], (const unsigned int*)d_in[10],
                       (const unsigned int*)d_in[11], flags);

    hipLaunchKernelGGL(cvt_f32_all, dim3((25218 + 255) / 256), dim3(256), 0, stream,
                       d_in[3], d_in[5], d_in[7], d_in[8], d_in[9], d_in[10], d_in[11],
                       flags, addff, b1f, b2f, fc1wf, fc1bf, fc2wf, fc2bf);
    hipLaunchKernelGGL(cvt_bf_all, dim3(64), dim3(256), 0, stream,
                       d_in[4], d_in[6], flags, W1p, W2p);

    hipLaunchKernelGGL(zero_i32, dim3((NN + 255) / 256), dim3(256), 0, stream, degi, NN);
    hipLaunchKernelGGL(deg_kernel, dim3((NE + 255) / 256), dim3(256), 0, stream,
                       ei, flags + 12, degi);
    hipLaunchKernelGGL(dinv_kernel, dim3((NN + 255) / 256), dim3(256), 0, stream,
                       degi, dinv);
    hipLaunchKernelGGL(scan1, dim3(NBLK), dim3(256), 0, stream, degi, escan, bsum);
    hipLaunchKernelGGL(scan2, dim3(1), dim3(256), 0, stream, bsum, boff);
    hipLaunchKernelGGL(scan3, dim3(NBLK), dim3(256), 0, stream, escan, boff,
                       rowst, cursor);
    hipLaunchKernelGGL(fill_kernel, dim3((EETOT + 255) / 256), dim3(256), 0, stream,
                       ei, flags + 12, dinv, cursor, cv);
    hipLaunchKernelGGL(gstart_kernel, dim3((NN + 255) / 256), dim3(256), 0, stream,
                       batch, flags + 13, gstart);

    hipLaunchKernelGGL(gemm, dim3((NN + 7) / 8), dim3(256), 0, stream,
                       d_in[0], flags + 0, W1p, bufA);
    hipLaunchKernelGGL(aggregate_kernel, dim3((NN + 3) / 4), dim3(256), 0, stream,
                       bufA, cv, rowst, b1f, bufB);
    hipLaunchKernelGGL(gemm, dim3((NN + 7) / 8), dim3(256), 0, stream,
                       bufB, flags + 14, W2p, bufA);
    hipLaunchKernelGGL(aggregate_kernel, dim3((NN + 3) / 4), dim3(256), 0, stream,
                       bufA, cv, rowst, b2f, bufB);

    hipLaunchKernelGGL(pool_seg, dim3(NG), dim3(64), 0, stream, bufB, gstart, sums);
    hipLaunchKernelGGL(head_kernel, dim3(NG), dim3(FD), 0, stream,
                       sums, gstart, addff, fc1wf, fc1bf, fc2wf, fc2bf,
                       flags + 0, d_out);
}

// Round 12
// 394.316 us; speedup vs baseline: 2.5819x; 1.1611x over previous
//
#include <hip/hip_runtime.h>

#define NN 50000
#define NE 800000
#define FD 128
#define FDH 64            // FD/2 packed bf16 pairs
#define FA 32
#define NG 128
#define EETOT (NE + NN)
#define NBLK ((NN + 255) / 256)   // 196 scan blocks

typedef __attribute__((ext_vector_type(8))) short short8;
typedef __attribute__((ext_vector_type(4))) float f32x4;

// ---------- bf16 helpers, pure bit ops ----------
__device__ __forceinline__ float bfbits(unsigned short u) {
    return __uint_as_float(((unsigned int)u) << 16);
}
__device__ __forceinline__ float bflo(unsigned int p) { return __uint_as_float(p << 16); }
__device__ __forceinline__ float bfhi(unsigned int p) { return __uint_as_float(p & 0xffff0000u); }
__device__ __forceinline__ unsigned short f2bf(float f) {   // RNE
    unsigned int u = __float_as_uint(f);
    unsigned int r = u + 0x7FFFu + ((u >> 16) & 1u);
    return (unsigned short)(r >> 16);
}
__device__ __forceinline__ unsigned int packbf(float a, float b) {
    return (unsigned int)f2bf(a) | ((unsigned int)f2bf(b) << 16);
}
__device__ __forceinline__ int ld_idx(const int* p, int i, int is64) {
    return is64 ? p[2 * i] : p[i];
}

// ---------- sentinels ----------
__global__ __launch_bounds__(128) void mark_kernel(float* out, float v) {
    out[threadIdx.x] = v;
}
__global__ __launch_bounds__(256) void zero_i32(int* p, int n) {
    int i = blockIdx.x * 256 + threadIdx.x;
    if (i < n) p[i] = 0;
}

// ---------- all dtype detection in one launch ----------
__global__ __launch_bounds__(64) void detect_all(
        const unsigned int* x, const int* ei, const int* batch,
        const unsigned int* addf, const unsigned int* w1, const unsigned int* b1,
        const unsigned int* w2, const unsigned int* b2, const unsigned int* fc1w,
        const unsigned int* fc1b, const unsigned int* fc2w, const unsigned int* fc2b,
        int* flags) {
    if (threadIdx.x != 0) return;
    int b = blockIdx.x;
    if (b < 10) {
        const unsigned int* t = x; int nw = 64; int idx = 0;
        switch (b) {
            case 0: t = x;    nw = 64; idx = 0;  break;
            case 1: t = addf; nw = 64; idx = 3;  break;
            case 2: t = w1;   nw = 64; idx = 4;  break;
            case 3: t = b1;   nw = 64; idx = 5;  break;
            case 4: t = w2;   nw = 64; idx = 6;  break;
            case 5: t = b2;   nw = 64; idx = 7;  break;
            case 6: t = fc1w; nw = 64; idx = 8;  break;
            case 7: t = fc1b; nw = 64; idx = 9;  break;
            case 8: t = fc2w; nw = 64; idx = 10; break;
            case 9: t = fc2b; nw = 1;  idx = 11; break;
        }
        int nz = 0, hits = 0;
        for (int i = 0; i < nw; ++i) {
            unsigned int w = t[i];
            if (w == 0u) continue;
            ++nz;
            unsigned int e = (w >> 7) & 0xFFu;
            if (e >= 100u && e <= 140u) ++hits;
        }
        flags[idx] = (nz < 8) ? 1 : (hits * 4 >= nz * 3);
    } else if (b == 10) {
        int odd_or = 0;
        for (int k = 0; k < 32; ++k) odd_or |= ei[2 * k + 1];
        flags[12] = (odd_or == 0) ? 1 : 0;
    } else {
        flags[13] = (batch[NN - 1] == 0) ? 1 : 0;   // sorted: tail nonzero iff int32
    }
}

// ---------- canonicalize fp32-destination weights (one launch) ----------
__global__ __launch_bounds__(256) void cvt_f32_all(
        const void* addf, const void* b1, const void* b2, const void* fc1w,
        const void* fc1b, const void* fc2w, const void* fc2b, const int* flags,
        float* addff, float* b1f, float* b2f, float* fc1wf,
        float* fc1bf, float* fc2wf, float* fc2bf) {
    int i = blockIdx.x * 256 + threadIdx.x;
    const void* src; float* dst; int flag; int rel;
    if      (i < 4096)  { src = addf; dst = addff; flag = flags[3];  rel = i; }
    else if (i < 4224)  { src = b1;   dst = b1f;   flag = flags[5];  rel = i - 4096; }
    else if (i < 4352)  { src = b2;   dst = b2f;   flag = flags[7];  rel = i - 4224; }
    else if (i < 24832) { src = fc1w; dst = fc1wf; flag = flags[8];  rel = i - 4352; }
    else if (i < 24960) { src = fc1b; dst = fc1bf; flag = flags[9];  rel = i - 24832; }
    else if (i < 25216) { src = fc2w; dst = fc2wf; flag = flags[10]; rel = i - 24960; }
    else if (i < 25218) { src = fc2b; dst = fc2bf; flag = flags[11]; rel = i - 25216; }
    else return;
    if (flag) dst[rel] = bfbits(((const unsigned short*)src)[rel]);
    else      dst[rel] = ((const float*)src)[rel];
}

// ---------- W1/W2 -> TRANSPOSED packed bf16: Wt[n][kk] = pack(W[2kk][n], W[2kk+1][n]) ----------
__global__ __launch_bounds__(256) void cvt_wt(const void* w1, const void* w2,
        const int* flags, unsigned int* W1t, unsigned int* W2t) {
    int i = blockIdx.x * 256 + threadIdx.x;
    if (i >= 16384) return;
    const void* src = (i < 8192) ? w1 : w2;
    unsigned int* dst = (i < 8192) ? W1t : W2t;
    int flag = (i < 8192) ? flags[4] : flags[6];
    int rel = i & 8191;
    int n = rel >> 6, kk = rel & 63;
    float lo, hi;
    if (flag) {
        const unsigned short* s = (const unsigned short*)src;
        lo = bfbits(s[(2 * kk) * FD + n]);
        hi = bfbits(s[(2 * kk + 1) * FD + n]);
    } else {
        const float* s = (const float*)src;
        lo = s[(2 * kk) * FD + n];
        hi = s[(2 * kk + 1) * FD + n];
    }
    dst[rel] = packbf(lo, hi);
}

// ---------- x -> packed bf16 ----------
__global__ __launch_bounds__(256) void cvt_x(const void* x, const int* xflag,
                                             unsigned int* out) {
    int i = blockIdx.x * 256 + threadIdx.x;
    if (i >= NN * FDH) return;
    if (*xflag) {
        out[i] = ((const unsigned int*)x)[i];
    } else {
        const float* s = (const float*)x;
        out[i] = packbf(s[2 * i], s[2 * i + 1]);
    }
}

// ---------- graph preprocessing ----------
__global__ __launch_bounds__(256) void deg_kernel(const int* ei, const int* iflag,
                                                  int* deg) {
    int e = blockIdx.x * 256 + threadIdx.x;
    int is64 = *iflag;
    if (e < NE) atomicAdd(&deg[ld_idx(ei, NE + e, is64)], 1);
}
__global__ __launch_bounds__(256) void dinv_kernel(const int* deg, float* dinv) {
    int i = blockIdx.x * 256 + threadIdx.x;
    if (i < NN) dinv[i] = rsqrtf((float)(deg[i] + 1));
}

// ---------- device-wide exclusive scan of (deg[i]+1), 3 phases ----------
__global__ __launch_bounds__(256) void scan1(const int* deg, int* escan, int* bsum) {
    __shared__ int sh[256];
    int i = blockIdx.x * 256 + threadIdx.x;
    int v = (i < NN) ? deg[i] + 1 : 0;
    sh[threadIdx.x] = v;
    __syncthreads();
    for (int off = 1; off < 256; off <<= 1) {
        int a = ((int)threadIdx.x >= off) ? sh[threadIdx.x - off] : 0;
        __syncthreads();
        sh[threadIdx.x] += a;
        __syncthreads();
    }
    if (i < NN) escan[i] = sh[threadIdx.x] - v;
    if (threadIdx.x == 255) bsum[blockIdx.x] = sh[255];
}
__global__ __launch_bounds__(256) void scan2(const int* bsum, int* boff) {
    __shared__ int sh[256];
    int t = threadIdx.x;
    int v = (t < NBLK) ? bsum[t] : 0;
    sh[t] = v;
    __syncthreads();
    for (int off = 1; off < 256; off <<= 1) {
        int a = (t >= off) ? sh[t - off] : 0;
        __syncthreads();
        sh[t] += a;
        __syncthreads();
    }
    if (t < NBLK) boff[t] = sh[t] - v;
}
__global__ __launch_bounds__(256) void scan3(const int* escan, const int* boff,
                                             int* rowstart, int* cursor) {
    int i = blockIdx.x * 256 + threadIdx.x;
    if (i < NN) {
        int r = escan[i] + boff[blockIdx.x];
        rowstart[i] = r;
        cursor[i]   = r;
    }
    if (i == 0) rowstart[NN] = EETOT;
}

// cv[pos] = {src, bits(norm)}
__global__ __launch_bounds__(256) void fill_kernel(const int* ei, const int* iflag,
        const float* dinv, int* cursor, int2* cv) {
    int e = blockIdx.x * 256 + threadIdx.x;
    if (e >= EETOT) return;
    int is64 = *iflag;
    int s, d;
    if (e < NE) { s = ld_idx(ei, e, is64); d = ld_idx(ei, NE + e, is64); }
    else        { s = d = e - NE; }
    int pos = atomicAdd(&cursor[d], 1);
    cv[pos] = make_int2(s, __float_as_int(dinv[s] * dinv[d]));
}

// ---------- graph boundaries (batch sorted) ----------
__global__ __launch_bounds__(256) void gstart_kernel(const int* batch, const int* bflag,
                                                     int* gstart) {
    int n = blockIdx.x * 256 + threadIdx.x;
    if (n >= NN) return;
    int is64 = *bflag;
    int bc = ld_idx(batch, n, is64);
    if (n == 0) {
        for (int g = 0; g <= bc; ++g) gstart[g] = 0;
    } else {
        int bp = ld_idx(batch, n - 1, is64);
        for (int g = bp + 1; g <= bc; ++g) gstart[g] = n;
    }
    if (n == NN - 1) {
        for (int g = bc + 1; g <= NG; ++g) gstart[g] = NN;
    }
}

// ---------- MFMA GEMM: C[NN][128] = A[NN][128] @ W[128][128], all bf16 ----------
// A packed bf16 rows; Wt transposed packed bf16 (Wt[n][k]); C ushort bf16.
// Wave = 16-row tile; 4 waves/block = 64 rows/block.
__global__ __launch_bounds__(256) void gemm_mfma(const unsigned int* __restrict__ A,
        const unsigned int* __restrict__ Wt, unsigned short* __restrict__ C) {
    int wave = threadIdx.x >> 6;
    int lane = threadIdx.x & 63;
    int quad = lane >> 4;
    int l16  = lane & 15;
    int mbase = blockIdx.x * 64 + wave * 16;
    int ra = mbase + l16;
    if (ra >= NN) ra = NN - 1;
    // A fragments for kk=0..3: A[ra][kk*32 + quad*8 + j], j=0..7 -> uint4
    short8 af[4];
    const uint4* Arow = (const uint4*)(A + (size_t)ra * FDH);
    #pragma unroll
    for (int kk = 0; kk < 4; ++kk) {
        uint4 v = Arow[kk * 4 + quad];
        af[kk] = *(short8*)&v;
    }
    #pragma unroll
    for (int nt = 0; nt < 8; ++nt) {
        int n = nt * 16 + l16;
        const uint4* Wrow = (const uint4*)(Wt + (size_t)n * FDH);
        f32x4 acc = {0.f, 0.f, 0.f, 0.f};
        #pragma unroll
        for (int kk = 0; kk < 4; ++kk) {
            uint4 wv = Wrow[kk * 4 + quad];
            short8 bf = *(short8*)&wv;
            acc = __builtin_amdgcn_mfma_f32_16x16x32_bf16(af[kk], bf, acc, 0, 0, 0);
        }
        int row0 = mbase + quad * 4;
        #pragma unroll
        for (int reg = 0; reg < 4; ++reg) {
            int r = row0 + reg;
            if (r < NN) C[(size_t)r * FD + nt * 16 + l16] = f2bf(acc[reg]);
        }
    }
}

// ---------- CSR aggregation (bf16 gather, unroll 4) + bias + relu -> bf16 ----------
__global__ __launch_bounds__(256) void aggregate_kernel(const unsigned int* Hb,
        const int2* cv, const int* rowstart, const float* bias, unsigned int* outb) {
    int n = blockIdx.x * 4 + (threadIdx.x >> 6);
    int cp = threadIdx.x & 63;
    if (n >= NN) return;
    int jb = rowstart[n], je = rowstart[n + 1];
    float acc0 = 0.f, acc1 = 0.f;
    int j = jb;
    for (; j + 3 < je; j += 4) {
        int2 e0 = cv[j], e1 = cv[j + 1], e2 = cv[j + 2], e3 = cv[j + 3];
        unsigned int h0 = Hb[(size_t)e0.x * FDH + cp];
        unsigned int h1 = Hb[(size_t)e1.x * FDH + cp];
        unsigned int h2 = Hb[(size_t)e2.x * FDH + cp];
        unsigned int h3 = Hb[(size_t)e3.x * FDH + cp];
        float v0 = __int_as_float(e0.y), v1 = __int_as_float(e1.y);
        float v2 = __int_as_float(e2.y), v3 = __int_as_float(e3.y);
        acc0 += v0 * bflo(h0) + v1 * bflo(h1) + v2 * bflo(h2) + v3 * bflo(h3);
        acc1 += v0 * bfhi(h0) + v1 * bfhi(h1) + v2 * bfhi(h2) + v3 * bfhi(h3);
    }
    for (; j < je; ++j) {
        int2 e0 = cv[j];
        unsigned int h0 = Hb[(size_t)e0.x * FDH + cp];
        float v0 = __int_as_float(e0.y);
        acc0 += v0 * bflo(h0);
        acc1 += v0 * bfhi(h0);
    }
    acc0 = fmaxf(acc0 + bias[2 * cp], 0.f);
    acc1 = fmaxf(acc1 + bias[2 * cp + 1], 0.f);
    outb[(size_t)n * FDH + cp] = packbf(acc0, acc1);
}

// ---------- segmented mean-pool over bf16 H ----------
__global__ __launch_bounds__(64) void pool_seg(const unsigned int* Hb, const int* gstart,
                                               float* sums) {
    int g = blockIdx.x;
    int cp = threadIdx.x;
    int s = gstart[g], e = gstart[g + 1];
    float a0 = 0.f, a1 = 0.f, b0 = 0.f, b1 = 0.f;
    int n = s;
    for (; n + 1 < e; n += 2) {
        unsigned int h0 = Hb[(size_t)n * FDH + cp];
        unsigned int h1 = Hb[(size_t)(n + 1) * FDH + cp];
        a0 += bflo(h0); a1 += bfhi(h0);
        b0 += bflo(h1); b1 += bfhi(h1);
    }
    if (n < e) {
        unsigned int h0 = Hb[(size_t)n * FDH + cp];
        a0 += bflo(h0); a1 += bfhi(h0);
    }
    sums[g * FD + 2 * cp]     = a0 + b0;
    sums[g * FD + 2 * cp + 1] = a1 + b1;
}

// ---------- head ----------
__global__ __launch_bounds__(128) void head_kernel(const float* sums, const int* gstart,
        const float* addf, const float* fc1w, const float* fc1b,
        const float* fc2w, const float* fc2b, const int* xflag, void* outp) {
    int g = blockIdx.x;
    int t = threadIdx.x;
    __shared__ float z[FD + FA];
    __shared__ float h[FD];
    float cnt = (float)(gstart[g + 1] - gstart[g]);
    if (cnt < 1.0f) cnt = 1.0f;
    z[t] = sums[g * FD + t] / cnt;
    if (t < FA) z[FD + t] = addf[g * FA + t];
    __syncthreads();
    float acc = fc1b[t];
    #pragma unroll 4
    for (int k = 0; k < FD + FA; ++k)
        acc += z[k] * fc1w[k * FD + t];
    h[t] = fmaxf(acc, 0.f);
    __syncthreads();
    if (t < 2) {
        float o = fc2b[t];
        for (int j = 0; j < FD; ++j) o += h[j] * fc2w[j * 2 + t];
        if (*xflag) ((unsigned short*)outp)[g * 2 + t] = f2bf(o);
        else        ((float*)outp)[g * 2 + t] = o;
    }
}

extern "C" void kernel_launch(void* const* d_in, const int* in_sizes, int n_in,
                              void* d_out, int out_size, void* d_ws, size_t ws_size,
                              hipStream_t stream) {
    (void)out_size;

    if (n_in != 12) {
        hipLaunchKernelGGL(mark_kernel, dim3(1), dim3(128), 0, stream,
                           (float*)d_out, 2000.0f);
        return;
    }
    const int exp_sizes[12] = {6400000, 1600000, 50000, 4096, 16384, 128,
                               16384, 128, 20480, 128, 256, 2};
    for (int i = 0; i < 12; ++i) {
        if (in_sizes[i] != exp_sizes[i]) {
            hipLaunchKernelGGL(mark_kernel, dim3(1), dim3(128), 0, stream,
                               (float*)d_out, 3000.0f + 100.0f * i);
            return;
        }
    }

    size_t off = 0;
    char* base = (char*)d_ws;
#define WSALLOC(ptr, type, nbytes) \
    type* ptr = (type*)(base + off); off += (((size_t)(nbytes)) + 255) & ~(size_t)255;
    WSALLOC(bufA,  unsigned int, (size_t)NN * FDH * 4)   // packed bf16 H
    WSALLOC(bufB,  unsigned int, (size_t)NN * FDH * 4)
    WSALLOC(bufC,  unsigned int, (size_t)NN * FDH * 4)   // x in packed bf16
    WSALLOC(dinv,  float, (size_t)NN * 4)
    WSALLOC(degi,  int,   (size_t)NN * 4)
    WSALLOC(rowst, int,   (size_t)(NN + 1) * 4)
    WSALLOC(cursor,int,   (size_t)NN * 4)
    WSALLOC(escan, int,   (size_t)NN * 4)
    WSALLOC(bsum,  int,   (size_t)NBLK * 4)
    WSALLOC(boff,  int,   (size_t)NBLK * 4)
    WSALLOC(cv,    int2,  (size_t)EETOT * 8)
    WSALLOC(sums,  float, (size_t)NG * FD * 4)
    WSALLOC(gstart,int,   (size_t)(NG + 1) * 4)
    WSALLOC(W1t,   unsigned int, (size_t)FD * FDH * 4)
    WSALLOC(W2t,   unsigned int, (size_t)FD * FDH * 4)
    WSALLOC(b1f,   float, FD * 4)
    WSALLOC(b2f,   float, FD * 4)
    WSALLOC(addff, float, (size_t)NG * FA * 4)
    WSALLOC(fc1wf, float, (size_t)(FD + FA) * FD * 4)
    WSALLOC(fc1bf, float, FD * 4)
    WSALLOC(fc2wf, float, FD * 2 * 4)
    WSALLOC(fc2bf, float, 2 * 4)
    WSALLOC(flags, int, 16 * 4)
#undef WSALLOC
    if (ws_size < off) {
        hipLaunchKernelGGL(mark_kernel, dim3(1), dim3(128), 0, stream,
                           (float*)d_out, 1000.0f);
        return;
    }

    const int* ei    = (const int*)d_in[1];
    const int* batch = (const int*)d_in[2];

    hipLaunchKernelGGL(detect_all, dim3(12), dim3(64), 0, stream,
                       (const unsigned int*)d_in[0], ei, batch,
                       (const unsigned int*)d_in[3], (const unsigned int*)d_in[4],
                       (const unsigned int*)d_in[5], (const unsigned int*)d_in[6],
                       (const unsigned int*)d_in[7], (const unsigned int*)d_in[8],
                       (const unsigned int*)d_in[9], (const unsigned int*)d_in[10],
                       (const unsigned int*)d_in[11], flags);

    hipLaunchKernelGGL(cvt_f32_all, dim3((25218 + 255) / 256), dim3(256), 0, stream,
                       d_in[3], d_in[5], d_in[7], d_in[8], d_in[9], d_in[10], d_in[11],
                       flags, addff, b1f, b2f, fc1wf, fc1bf, fc2wf, fc2bf);
    hipLaunchKernelGGL(cvt_wt, dim3(64), dim3(256), 0, stream,
                       d_in[4], d_in[6], flags, W1t, W2t);
    hipLaunchKernelGGL(cvt_x, dim3((NN * FDH + 255) / 256), dim3(256), 0, stream,
                       d_in[0], flags + 0, bufC);

    hipLaunchKernelGGL(zero_i32, dim3((NN + 255) / 256), dim3(256), 0, stream, degi, NN);
    hipLaunchKernelGGL(deg_kernel, dim3((NE + 255) / 256), dim3(256), 0, stream,
                       ei, flags + 12, degi);
    hipLaunchKernelGGL(dinv_kernel, dim3((NN + 255) / 256), dim3(256), 0, stream,
                       degi, dinv);
    hipLaunchKernelGGL(scan1, dim3(NBLK), dim3(256), 0, stream, degi, escan, bsum);
    hipLaunchKernelGGL(scan2, dim3(1), dim3(256), 0, stream, bsum, boff);
    hipLaunchKernelGGL(scan3, dim3(NBLK), dim3(256), 0, stream, escan, boff,
                       rowst, cursor);
    hipLaunchKernelGGL(fill_kernel, dim3((EETOT + 255) / 256), dim3(256), 0, stream,
                       ei, flags + 12, dinv, cursor, cv);
    hipLaunchKernelGGL(gstart_kernel, dim3((NN + 255) / 256), dim3(256), 0, stream,
                       batch, flags + 13, gstart);

    hipLaunchKernelGGL(gemm_mfma, dim3((NN + 63) / 64), dim3(256), 0, stream,
                       bufC, W1t, (unsigned short*)bufA);
    hipLaunchKernelGGL(aggregate_kernel, dim3((NN + 3) / 4), dim3(256), 0, stream,
                       bufA, cv, rowst, b1f, bufB);
    hipLaunchKernelGGL(gemm_mfma, dim3((NN + 63) / 64), dim3(256), 0, stream,
                       bufB, W2t, (unsigned short*)bufA);
    hipLaunchKernelGGL(aggregate_kernel, dim3((NN + 3) / 4), dim3(256), 0, stream,
                       bufA, cv, rowst, b2f, bufB);

    hipLaunchKernelGGL(pool_seg, dim3(NG), dim3(64), 0, stream, bufB, gstart, sums);
    hipLaunchKernelGGL(head_kernel, dim3(NG), dim3(FD), 0, stream,
                       sums, gstart, addff, fc1wf, fc1bf, fc2wf, fc2bf,
                       flags + 0, d_out);
}

// Round 13
// 352.315 us; speedup vs baseline: 2.8897x; 1.1192x over previous
//
#include <hip/hip_runtime.h>

#define NN 50000
#define NE 800000
#define FD 128
#define FDH 64            // FD/2 packed bf16 pairs
#define FA 32
#define NG 128
#define EETOT (NE + NN)
#define NBLK ((NN + 255) / 256)   // 196 scan blocks
#define PK 8                      // pool partial slices per graph

typedef __attribute__((ext_vector_type(8))) short short8;
typedef __attribute__((ext_vector_type(4))) float f32x4;

// ---------- bf16 helpers, pure bit ops ----------
__device__ __forceinline__ float bfbits(unsigned short u) {
    return __uint_as_float(((unsigned int)u) << 16);
}
__device__ __forceinline__ float bflo(unsigned int p) { return __uint_as_float(p << 16); }
__device__ __forceinline__ float bfhi(unsigned int p) { return __uint_as_float(p & 0xffff0000u); }
__device__ __forceinline__ unsigned short f2bf(float f) {   // RNE
    unsigned int u = __float_as_uint(f);
    unsigned int r = u + 0x7FFFu + ((u >> 16) & 1u);
    return (unsigned short)(r >> 16);
}
__device__ __forceinline__ unsigned int packbf(float a, float b) {
    return (unsigned int)f2bf(a) | ((unsigned int)f2bf(b) << 16);
}
__device__ __forceinline__ int ld_idx(const int* p, int i, int is64) {
    return is64 ? p[2 * i] : p[i];
}

// ---------- sentinels ----------
__global__ __launch_bounds__(128) void mark_kernel(float* out, float v) {
    out[threadIdx.x] = v;
}
__global__ __launch_bounds__(256) void zero_i32(int* p, int n) {
    int i = blockIdx.x * 256 + threadIdx.x;
    if (i < n) p[i] = 0;
}

// ---------- all dtype detection in one launch ----------
__global__ __launch_bounds__(64) void detect_all(
        const unsigned int* x, const int* ei, const int* batch,
        const unsigned int* addf, const unsigned int* w1, const unsigned int* b1,
        const unsigned int* w2, const unsigned int* b2, const unsigned int* fc1w,
        const unsigned int* fc1b, const unsigned int* fc2w, const unsigned int* fc2b,
        int* flags) {
    if (threadIdx.x != 0) return;
    int b = blockIdx.x;
    if (b < 10) {
        const unsigned int* t = x; int nw = 64; int idx = 0;
        switch (b) {
            case 0: t = x;    nw = 64; idx = 0;  break;
            case 1: t = addf; nw = 64; idx = 3;  break;
            case 2: t = w1;   nw = 64; idx = 4;  break;
            case 3: t = b1;   nw = 64; idx = 5;  break;
            case 4: t = w2;   nw = 64; idx = 6;  break;
            case 5: t = b2;   nw = 64; idx = 7;  break;
            case 6: t = fc1w; nw = 64; idx = 8;  break;
            case 7: t = fc1b; nw = 64; idx = 9;  break;
            case 8: t = fc2w; nw = 64; idx = 10; break;
            case 9: t = fc2b; nw = 1;  idx = 11; break;
        }
        int nz = 0, hits = 0;
        for (int i = 0; i < nw; ++i) {
            unsigned int w = t[i];
            if (w == 0u) continue;
            ++nz;
            unsigned int e = (w >> 7) & 0xFFu;
            if (e >= 100u && e <= 140u) ++hits;
        }
        flags[idx] = (nz < 8) ? 1 : (hits * 4 >= nz * 3);
    } else if (b == 10) {
        int odd_or = 0;
        for (int k = 0; k < 32; ++k) odd_or |= ei[2 * k + 1];
        flags[12] = (odd_or == 0) ? 1 : 0;
    } else {
        flags[13] = (batch[NN - 1] == 0) ? 1 : 0;   // sorted: tail nonzero iff int32
    }
}

// ---------- canonicalize fp32-destination weights (one launch) ----------
__global__ __launch_bounds__(256) void cvt_f32_all(
        const void* addf, const void* b1, const void* b2, const void* fc1w,
        const void* fc1b, const void* fc2w, const void* fc2b, const int* flags,
        float* addff, float* b1f, float* b2f, float* fc1wf,
        float* fc1bf, float* fc2wf, float* fc2bf) {
    int i = blockIdx.x * 256 + threadIdx.x;
    const void* src; float* dst; int flag; int rel;
    if      (i < 4096)  { src = addf; dst = addff; flag = flags[3];  rel = i; }
    else if (i < 4224)  { src = b1;   dst = b1f;   flag = flags[5];  rel = i - 4096; }
    else if (i < 4352)  { src = b2;   dst = b2f;   flag = flags[7];  rel = i - 4224; }
    else if (i < 24832) { src = fc1w; dst = fc1wf; flag = flags[8];  rel = i - 4352; }
    else if (i < 24960) { src = fc1b; dst = fc1bf; flag = flags[9];  rel = i - 24832; }
    else if (i < 25216) { src = fc2w; dst = fc2wf; flag = flags[10]; rel = i - 24960; }
    else if (i < 25218) { src = fc2b; dst = fc2bf; flag = flags[11]; rel = i - 25216; }
    else return;
    if (flag) dst[rel] = bfbits(((const unsigned short*)src)[rel]);
    else      dst[rel] = ((const float*)src)[rel];
}

// ---------- W1/W2 -> TRANSPOSED packed bf16: Wt[n][kk] = pack(W[2kk][n], W[2kk+1][n]) ----------
__global__ __launch_bounds__(256) void cvt_wt(const void* w1, const void* w2,
        const int* flags, unsigned int* W1t, unsigned int* W2t) {
    int i = blockIdx.x * 256 + threadIdx.x;
    if (i >= 16384) return;
    const void* src = (i < 8192) ? w1 : w2;
    unsigned int* dst = (i < 8192) ? W1t : W2t;
    int flag = (i < 8192) ? flags[4] : flags[6];
    int rel = i & 8191;
    int n = rel >> 6, kk = rel & 63;
    float lo, hi;
    if (flag) {
        const unsigned short* s = (const unsigned short*)src;
        lo = bfbits(s[(2 * kk) * FD + n]);
        hi = bfbits(s[(2 * kk + 1) * FD + n]);
    } else {
        const float* s = (const float*)src;
        lo = s[(2 * kk) * FD + n];
        hi = s[(2 * kk + 1) * FD + n];
    }
    dst[rel] = packbf(lo, hi);
}

// ---------- x -> packed bf16 ----------
__global__ __launch_bounds__(256) void cvt_x(const void* x, const int* xflag,
                                             unsigned int* out) {
    int i = blockIdx.x * 256 + threadIdx.x;
    if (i >= NN * FDH) return;
    if (*xflag) {
        out[i] = ((const unsigned int*)x)[i];
    } else {
        const float* s = (const float*)x;
        out[i] = packbf(s[2 * i], s[2 * i + 1]);
    }
}

// ---------- graph preprocessing ----------
__global__ __launch_bounds__(256) void deg_kernel(const int* ei, const int* iflag,
                                                  int* deg) {
    int e = blockIdx.x * 256 + threadIdx.x;
    int is64 = *iflag;
    if (e < NE) atomicAdd(&deg[ld_idx(ei, NE + e, is64)], 1);
}
__global__ __launch_bounds__(256) void dinv_kernel(const int* deg, float* dinv) {
    int i = blockIdx.x * 256 + threadIdx.x;
    if (i < NN) dinv[i] = rsqrtf((float)(deg[i] + 1));
}

// ---------- device-wide exclusive scan of (deg[i]+1), 3 phases ----------
__global__ __launch_bounds__(256) void scan1(const int* deg, int* escan, int* bsum) {
    __shared__ int sh[256];
    int i = blockIdx.x * 256 + threadIdx.x;
    int v = (i < NN) ? deg[i] + 1 : 0;
    sh[threadIdx.x] = v;
    __syncthreads();
    for (int off = 1; off < 256; off <<= 1) {
        int a = ((int)threadIdx.x >= off) ? sh[threadIdx.x - off] : 0;
        __syncthreads();
        sh[threadIdx.x] += a;
        __syncthreads();
    }
    if (i < NN) escan[i] = sh[threadIdx.x] - v;
    if (threadIdx.x == 255) bsum[blockIdx.x] = sh[255];
}
__global__ __launch_bounds__(256) void scan2(const int* bsum, int* boff) {
    __shared__ int sh[256];
    int t = threadIdx.x;
    int v = (t < NBLK) ? bsum[t] : 0;
    sh[t] = v;
    __syncthreads();
    for (int off = 1; off < 256; off <<= 1) {
        int a = (t >= off) ? sh[t - off] : 0;
        __syncthreads();
        sh[t] += a;
        __syncthreads();
    }
    if (t < NBLK) boff[t] = sh[t] - v;
}
__global__ __launch_bounds__(256) void scan3(const int* escan, const int* boff,
                                             int* rowstart, int* cursor) {
    int i = blockIdx.x * 256 + threadIdx.x;
    if (i < NN) {
        int r = escan[i] + boff[blockIdx.x];
        rowstart[i] = r;
        cursor[i]   = r;
    }
    if (i == 0) rowstart[NN] = EETOT;
}

// cv[pos] = {src, bits(norm)}
__global__ __launch_bounds__(256) void fill_kernel(const int* ei, const int* iflag,
        const float* dinv, int* cursor, int2* cv) {
    int e = blockIdx.x * 256 + threadIdx.x;
    if (e >= EETOT) return;
    int is64 = *iflag;
    int s, d;
    if (e < NE) { s = ld_idx(ei, e, is64); d = ld_idx(ei, NE + e, is64); }
    else        { s = d = e - NE; }
    int pos = atomicAdd(&cursor[d], 1);
    cv[pos] = make_int2(s, __float_as_int(dinv[s] * dinv[d]));
}

// ---------- graph boundaries (batch sorted) ----------
__global__ __launch_bounds__(256) void gstart_kernel(const int* batch, const int* bflag,
                                                     int* gstart) {
    int n = blockIdx.x * 256 + threadIdx.x;
    if (n >= NN) return;
    int is64 = *bflag;
    int bc = ld_idx(batch, n, is64);
    if (n == 0) {
        for (int g = 0; g <= bc; ++g) gstart[g] = 0;
    } else {
        int bp = ld_idx(batch, n - 1, is64);
        for (int g = bp + 1; g <= bc; ++g) gstart[g] = n;
    }
    if (n == NN - 1) {
        for (int g = bc + 1; g <= NG; ++g) gstart[g] = NN;
    }
}

// ---------- MFMA GEMM: C[NN][128] = A[NN][128] @ W[128][128], all bf16 ----------
__global__ __launch_bounds__(256) void gemm_mfma(const unsigned int* __restrict__ A,
        const unsigned int* __restrict__ Wt, unsigned short* __restrict__ C) {
    int wave = threadIdx.x >> 6;
    int lane = threadIdx.x & 63;
    int quad = lane >> 4;
    int l16  = lane & 15;
    int mbase = blockIdx.x * 64 + wave * 16;
    int ra = mbase + l16;
    if (ra >= NN) ra = NN - 1;
    short8 af[4];
    const uint4* Arow = (const uint4*)(A + (size_t)ra * FDH);
    #pragma unroll
    for (int kk = 0; kk < 4; ++kk) {
        uint4 v = Arow[kk * 4 + quad];
        af[kk] = *(short8*)&v;
    }
    #pragma unroll
    for (int nt = 0; nt < 8; ++nt) {
        int n = nt * 16 + l16;
        const uint4* Wrow = (const uint4*)(Wt + (size_t)n * FDH);
        f32x4 acc = {0.f, 0.f, 0.f, 0.f};
        #pragma unroll
        for (int kk = 0; kk < 4; ++kk) {
            uint4 wv = Wrow[kk * 4 + quad];
            short8 bf = *(short8*)&wv;
            acc = __builtin_amdgcn_mfma_f32_16x16x32_bf16(af[kk], bf, acc, 0, 0, 0);
        }
        int row0 = mbase + quad * 4;
        #pragma unroll
        for (int reg = 0; reg < 4; ++reg) {
            int r = row0 + reg;
            if (r < NN) C[(size_t)r * FD + nt * 16 + l16] = f2bf(acc[reg]);
        }
    }
}

// ---------- CSR aggregation (bf16 gather, unroll 4) + bias + relu -> bf16 ----------
__global__ __launch_bounds__(256) void aggregate_kernel(const unsigned int* Hb,
        const int2* cv, const int* rowstart, const float* bias, unsigned int* outb) {
    int n = blockIdx.x * 4 + (threadIdx.x >> 6);
    int cp = threadIdx.x & 63;
    if (n >= NN) return;
    int jb = rowstart[n], je = rowstart[n + 1];
    float acc0 = 0.f, acc1 = 0.f;
    int j = jb;
    for (; j + 3 < je; j += 4) {
        int2 e0 = cv[j], e1 = cv[j + 1], e2 = cv[j + 2], e3 = cv[j + 3];
        unsigned int h0 = Hb[(size_t)e0.x * FDH + cp];
        unsigned int h1 = Hb[(size_t)e1.x * FDH + cp];
        unsigned int h2 = Hb[(size_t)e2.x * FDH + cp];
        unsigned int h3 = Hb[(size_t)e3.x * FDH + cp];
        float v0 = __int_as_float(e0.y), v1 = __int_as_float(e1.y);
        float v2 = __int_as_float(e2.y), v3 = __int_as_float(e3.y);
        acc0 += v0 * bflo(h0) + v1 * bflo(h1) + v2 * bflo(h2) + v3 * bflo(h3);
        acc1 += v0 * bfhi(h0) + v1 * bfhi(h1) + v2 * bfhi(h2) + v3 * bfhi(h3);
    }
    for (; j < je; ++j) {
        int2 e0 = cv[j];
        unsigned int h0 = Hb[(size_t)e0.x * FDH + cp];
        float v0 = __int_as_float(e0.y);
        acc0 += v0 * bflo(h0);
        acc1 += v0 * bfhi(h0);
    }
    acc0 = fmaxf(acc0 + bias[2 * cp], 0.f);
    acc1 = fmaxf(acc1 + bias[2 * cp + 1], 0.f);
    outb[(size_t)n * FDH + cp] = packbf(acc0, acc1);
}

// ---------- 2-phase segmented mean-pool: 8 slices/graph then reduce ----------
__global__ __launch_bounds__(64) void pool_part(const unsigned int* Hb,
        const int* gstart, float* part) {
    int g = blockIdx.x >> 3;
    int k = blockIdx.x & (PK - 1);
    int cp = threadIdx.x;
    int s = gstart[g], e = gstart[g + 1];
    int len = e - s;
    int per = (len + PK - 1) / PK;
    int ss = s + k * per;
    int ee = ss + per; if (ee > e) ee = e;
    float a0 = 0.f, a1 = 0.f, b0 = 0.f, b1 = 0.f;
    int n = ss;
    for (; n + 1 < ee; n += 2) {
        unsigned int h0 = Hb[(size_t)n * FDH + cp];
        unsigned int h1 = Hb[(size_t)(n + 1) * FDH + cp];
        a0 += bflo(h0); a1 += bfhi(h0);
        b0 += bflo(h1); b1 += bfhi(h1);
    }
    if (n < ee) {
        unsigned int h0 = Hb[(size_t)n * FDH + cp];
        a0 += bflo(h0); a1 += bfhi(h0);
    }
    part[(size_t)(g * PK + k) * FD + 2 * cp]     = a0 + b0;
    part[(size_t)(g * PK + k) * FD + 2 * cp + 1] = a1 + b1;
}
__global__ __launch_bounds__(128) void pool_red(const float* part, float* sums) {
    int g = blockIdx.x;
    int c = threadIdx.x;
    float a = 0.f;
    #pragma unroll
    for (int k = 0; k < PK; ++k) a += part[(size_t)(g * PK + k) * FD + c];
    sums[g * FD + c] = a;
}

// ---------- head ----------
__global__ __launch_bounds__(128) void head_kernel(const float* sums, const int* gstart,
        const float* addf, const float* fc1w, const float* fc1b,
        const float* fc2w, const float* fc2b, const int* xflag, void* outp) {
    int g = blockIdx.x;
    int t = threadIdx.x;
    __shared__ float z[FD + FA];
    __shared__ float h[FD];
    float cnt = (float)(gstart[g + 1] - gstart[g]);
    if (cnt < 1.0f) cnt = 1.0f;
    z[t] = sums[g * FD + t] / cnt;
    if (t < FA) z[FD + t] = addf[g * FA + t];
    __syncthreads();
    float acc = fc1b[t];
    #pragma unroll 4
    for (int k = 0; k < FD + FA; ++k)
        acc += z[k] * fc1w[k * FD + t];
    h[t] = fmaxf(acc, 0.f);
    __syncthreads();
    if (t < 2) {
        float o = fc2b[t];
        for (int j = 0; j < FD; ++j) o += h[j] * fc2w[j * 2 + t];
        if (*xflag) ((unsigned short*)outp)[g * 2 + t] = f2bf(o);
        else        ((float*)outp)[g * 2 + t] = o;
    }
}

extern "C" void kernel_launch(void* const* d_in, const int* in_sizes, int n_in,
                              void* d_out, int out_size, void* d_ws, size_t ws_size,
                              hipStream_t stream) {
    (void)out_size;

    if (n_in != 12) {
        hipLaunchKernelGGL(mark_kernel, dim3(1), dim3(128), 0, stream,
                           (float*)d_out, 2000.0f);
        return;
    }
    const int exp_sizes[12] = {6400000, 1600000, 50000, 4096, 16384, 128,
                               16384, 128, 20480, 128, 256, 2};
    for (int i = 0; i < 12; ++i) {
        if (in_sizes[i] != exp_sizes[i]) {
            hipLaunchKernelGGL(mark_kernel, dim3(1), dim3(128), 0, stream,
                               (float*)d_out, 3000.0f + 100.0f * i);
            return;
        }
    }

    size_t off = 0;
    char* base = (char*)d_ws;
#define WSALLOC(ptr, type, nbytes) \
    type* ptr = (type*)(base + off); off += (((size_t)(nbytes)) + 255) & ~(size_t)255;
    WSALLOC(bufA,  unsigned int, (size_t)NN * FDH * 4)   // packed bf16 H
    WSALLOC(bufB,  unsigned int, (size_t)NN * FDH * 4)
    WSALLOC(bufC,  unsigned int, (size_t)NN * FDH * 4)   // x in packed bf16
    WSALLOC(dinv,  float, (size_t)NN * 4)
    WSALLOC(degi,  int,   (size_t)NN * 4)
    WSALLOC(rowst, int,   (size_t)(NN + 1) * 4)
    WSALLOC(cursor,int,   (size_t)NN * 4)
    WSALLOC(escan, int,   (size_t)NN * 4)
    WSALLOC(bsum,  int,   (size_t)NBLK * 4)
    WSALLOC(boff,  int,   (size_t)NBLK * 4)
    WSALLOC(cv,    int2,  (size_t)EETOT * 8)
    WSALLOC(part,  float, (size_t)NG * PK * FD * 4)
    WSALLOC(sums,  float, (size_t)NG * FD * 4)
    WSALLOC(gstart,int,   (size_t)(NG + 1) * 4)
    WSALLOC(W1t,   unsigned int, (size_t)FD * FDH * 4)
    WSALLOC(W2t,   unsigned int, (size_t)FD * FDH * 4)
    WSALLOC(b1f,   float, FD * 4)
    WSALLOC(b2f,   float, FD * 4)
    WSALLOC(addff, float, (size_t)NG * FA * 4)
    WSALLOC(fc1wf, float, (size_t)(FD + FA) * FD * 4)
    WSALLOC(fc1bf, float, FD * 4)
    WSALLOC(fc2wf, float, FD * 2 * 4)
    WSALLOC(fc2bf, float, 2 * 4)
    WSALLOC(flags, int, 16 * 4)
#undef WSALLOC
    if (ws_size < off) {
        hipLaunchKernelGGL(mark_kernel, dim3(1), dim3(128), 0, stream,
                           (float*)d_out, 1000.0f);
        return;
    }

    const int* ei    = (const int*)d_in[1];
    const int* batch = (const int*)d_in[2];

    hipLaunchKernelGGL(detect_all, dim3(12), dim3(64), 0, stream,
                       (const unsigned int*)d_in[0], ei, batch,
                       (const unsigned int*)d_in[3], (const unsigned int*)d_in[4],
                       (const unsigned int*)d_in[5], (const unsigned int*)d_in[6],
                       (const unsigned int*)d_in[7], (const unsigned int*)d_in[8],
                       (const unsigned int*)d_in[9], (const unsigned int*)d_in[10],
                       (const unsigned int*)d_in[11], flags);

    hipLaunchKernelGGL(cvt_f32_all, dim3((25218 + 255) / 256), dim3(256), 0, stream,
                       d_in[3], d_in[5], d_in[7], d_in[8], d_in[9], d_in[10], d_in[11],
                       flags, addff, b1f, b2f, fc1wf, fc1bf, fc2wf, fc2bf);
    hipLaunchKernelGGL(cvt_wt, dim3(64), dim3(256), 0, stream,
                       d_in[4], d_in[6], flags, W1t, W2t);
    hipLaunchKernelGGL(cvt_x, dim3((NN * FDH + 255) / 256), dim3(256), 0, stream,
                       d_in[0], flags + 0, bufC);

    hipLaunchKernelGGL(zero_i32, dim3((NN + 255) / 256), dim3(256), 0, stream, degi, NN);
    hipLaunchKernelGGL(deg_kernel, dim3((NE + 255) / 256), dim3(256), 0, stream,
                       ei, flags + 12, degi);
    hipLaunchKernelGGL(dinv_kernel, dim3((NN + 255) / 256), dim3(256), 0, stream,
                       degi, dinv);
    hipLaunchKernelGGL(scan1, dim3(NBLK), dim3(256), 0, stream, degi, escan, bsum);
    hipLaunchKernelGGL(scan2, dim3(1), dim3(256), 0, stream, bsum, boff);
    hipLaunchKernelGGL(scan3, dim3(NBLK), dim3(256), 0, stream, escan, boff,
                       rowst, cursor);
    hipLaunchKernelGGL(fill_kernel, dim3((EETOT + 255) / 256), dim3(256), 0, stream,
                       ei, flags + 12, dinv, cursor, cv);
    hipLaunchKernelGGL(gstart_kernel, dim3((NN + 255) / 256), dim3(256), 0, stream,
                       batch, flags + 13, gstart);

    hipLaunchKernelGGL(gemm_mfma, dim3((NN + 63) / 64), dim3(256), 0, stream,
                       bufC, W1t, (unsigned short*)bufA);
    hipLaunchKernelGGL(aggregate_kernel, dim3((NN + 3) / 4), dim3(256), 0, stream,
                       bufA, cv, rowst, b1f, bufB);
    hipLaunchKernelGGL(gemm_mfma, dim3((NN + 63) / 64), dim3(256), 0, stream,
                       bufB, W2t, (unsigned short*)bufA);
    hipLaunchKernelGGL(aggregate_kernel, dim3((NN + 3) / 4), dim3(256), 0, stream,
                       bufA, cv, rowst, b2f, bufB);

    hipLaunchKernelGGL(pool_part, dim3(NG * PK), dim3(64), 0, stream,
                       bufB, gstart, part);
    hipLaunchKernelGGL(pool_red, dim3(NG), dim3(128), 0, stream, part, sums);
    hipLaunchKernelGGL(head_kernel, dim3(NG), dim3(FD), 0, stream,
                       sums, gstart, addff, fc1wf, fc1bf, fc2wf, fc2bf,
                       flags + 0, d_out);
}

// Round 14
// 344.352 us; speedup vs baseline: 2.9565x; 1.0231x over previous
//
#include <hip/hip_runtime.h>

#define NN 50000
#define NE 800000
#define FD 128
#define FDH 64            // FD/2 packed bf16 pairs
#define FA 32
#define NG 128
#define EETOT (NE + NN)
#define NBLK ((NN + 255) / 256)   // 196 scan blocks
#define PK 8                      // pool partial slices per graph

typedef __attribute__((ext_vector_type(8))) short short8;
typedef __attribute__((ext_vector_type(4))) float f32x4;

// ---------- bf16 helpers ----------
__device__ __forceinline__ float bfbits(unsigned short u) {
    return __uint_as_float(((unsigned int)u) << 16);
}
__device__ __forceinline__ float bflo(unsigned int p) { return __uint_as_float(p << 16); }
__device__ __forceinline__ float bfhi(unsigned int p) { return __uint_as_float(p & 0xffff0000u); }
__device__ __forceinline__ unsigned short f2bf(float f) {   // RNE
    unsigned int u = __float_as_uint(f);
    unsigned int r = u + 0x7FFFu + ((u >> 16) & 1u);
    return (unsigned short)(r >> 16);
}
__device__ __forceinline__ unsigned int packbf(float a, float b) {
    return (unsigned int)f2bf(a) | ((unsigned int)f2bf(b) << 16);
}
__device__ __forceinline__ int ld_idx(const int* p, int i, int is64) {
    return is64 ? p[2 * i] : p[i];
}
// bf16-packed detection probe (same semantics as earlier rounds)
__device__ int probe_bf16(const unsigned int* t, int nwords) {
    int nz = 0, hits = 0;
    for (int i = 0; i < nwords; ++i) {
        unsigned int w = t[i];
        if (w == 0u) continue;
        ++nz;
        unsigned int e = (w >> 7) & 0xFFu;
        if (e >= 100u && e <= 140u) ++hits;
    }
    return (nz < 8) ? 1 : (hits * 4 >= nz * 3);
}

// ---------- sentinels ----------
__global__ __launch_bounds__(128) void mark_kernel(float* out, float v) {
    out[threadIdx.x] = v;
}

// ---------- fused prep: canonicalize everything + flags + zero degi ----------
// blocks [0,12500): x -> packed bf16 bufC
// blocks [12500,12564): W1/W2 -> transposed packed bf16
// blocks [12564,12663): all fp32-dest weights
// block 12663: flags[0]=x bf16, flags[12]=ei is64, flags[13]=batch is64
// blocks [12664,12860): zero degi
__global__ __launch_bounds__(256) void prep(
        const void* x, const int* ei, const int* batch, const void* addf,
        const void* w1, const void* b1, const void* w2, const void* b2,
        const void* fc1w, const void* fc1b, const void* fc2w, const void* fc2b,
        unsigned int* bufC, unsigned int* W1t, unsigned int* W2t,
        float* addff, float* b1f, float* b2f, float* fc1wf, float* fc1bf,
        float* fc2wf, float* fc2bf, int* flags, int* degi) {
    int b = blockIdx.x;
    if (b < 12500) {
        __shared__ int sflag;
        if (threadIdx.x == 0) sflag = probe_bf16((const unsigned int*)x, 64);
        __syncthreads();
        int i = b * 256 + threadIdx.x;           // < NN*FDH = 3.2M
        if (sflag) {
            bufC[i] = ((const unsigned int*)x)[i];
        } else {
            const float* s = (const float*)x;
            bufC[i] = packbf(s[2 * i], s[2 * i + 1]);
        }
    } else if (b < 12564) {
        int rel = (b - 12500) * 256 + threadIdx.x;   // [0,16384), no tensor straddle
        const void* src = (rel < 8192) ? w1 : w2;
        unsigned int* dst = (rel < 8192) ? W1t : W2t;
        __shared__ int sflag;
        if (threadIdx.x == 0) sflag = probe_bf16((const unsigned int*)src, 64);
        __syncthreads();
        int rr = rel & 8191;
        int n = rr >> 6, kk = rr & 63;
        float lo, hi;
        if (sflag) {
            const unsigned short* s = (const unsigned short*)src;
            lo = bfbits(s[(2 * kk) * FD + n]);
            hi = bfbits(s[(2 * kk + 1) * FD + n]);
        } else {
            const float* s = (const float*)src;
            lo = s[(2 * kk) * FD + n];
            hi = s[(2 * kk + 1) * FD + n];
        }
        dst[rr] = packbf(lo, hi);
    } else if (b < 12663) {
        __shared__ int sf[7];
        if (threadIdx.x == 0) {
            sf[0] = probe_bf16((const unsigned int*)addf, 64);
            sf[1] = probe_bf16((const unsigned int*)b1, 64);
            sf[2] = probe_bf16((const unsigned int*)b2, 64);
            sf[3] = probe_bf16((const unsigned int*)fc1w, 64);
            sf[4] = probe_bf16((const unsigned int*)fc1b, 64);
            sf[5] = probe_bf16((const unsigned int*)fc2w, 64);
            sf[6] = probe_bf16((const unsigned int*)fc2b, 1);
        }
        __syncthreads();
        int i = (b - 12564) * 256 + threadIdx.x;     // [0,25344)
        const void* src; float* dst; int flag; int rel;
        if      (i < 4096)  { src = addf; dst = addff; flag = sf[0]; rel = i; }
        else if (i < 4224)  { src = b1;   dst = b1f;   flag = sf[1]; rel = i - 4096; }
        else if (i < 4352)  { src = b2;   dst = b2f;   flag = sf[2]; rel = i - 4224; }
        else if (i < 24832) { src = fc1w; dst = fc1wf; flag = sf[3]; rel = i - 4352; }
        else if (i < 24960) { src = fc1b; dst = fc1bf; flag = sf[4]; rel = i - 24832; }
        else if (i < 25216) { src = fc2w; dst = fc2wf; flag = sf[5]; rel = i - 24960; }
        else if (i < 25218) { src = fc2b; dst = fc2bf; flag = sf[6]; rel = i - 25216; }
        else return;
        if (flag) dst[rel] = bfbits(((const unsigned short*)src)[rel]);
        else      dst[rel] = ((const float*)src)[rel];
    } else if (b == 12663) {
        if (threadIdx.x == 0) {
            flags[0] = probe_bf16((const unsigned int*)x, 64);
            int odd_or = 0;
            for (int k = 0; k < 32; ++k) odd_or |= ei[2 * k + 1];
            flags[12] = (odd_or == 0) ? 1 : 0;
            flags[13] = (batch[NN - 1] == 0) ? 1 : 0;
        }
    } else {
        int i = (b - 12664) * 256 + threadIdx.x;
        if (i < NN) degi[i] = 0;
    }
}

// ---------- degree ----------
__global__ __launch_bounds__(256) void deg_kernel(const int* ei, const int* flags,
                                                  int* deg) {
    int e = blockIdx.x * 256 + threadIdx.x;
    int is64 = flags[12];
    if (e < NE) atomicAdd(&deg[ld_idx(ei, NE + e, is64)], 1);
}

// ---------- scan phase 1 (+ dinv fused) ----------
__global__ __launch_bounds__(256) void scan1(const int* deg, float* dinv,
                                             int* escan, int* bsum) {
    __shared__ int sh[256];
    int i = blockIdx.x * 256 + threadIdx.x;
    int d = (i < NN) ? deg[i] : 0;
    if (i < NN) dinv[i] = rsqrtf((float)(d + 1));
    int v = (i < NN) ? d + 1 : 0;
    sh[threadIdx.x] = v;
    __syncthreads();
    for (int off = 1; off < 256; off <<= 1) {
        int a = ((int)threadIdx.x >= off) ? sh[threadIdx.x - off] : 0;
        __syncthreads();
        sh[threadIdx.x] += a;
        __syncthreads();
    }
    if (i < NN) escan[i] = sh[threadIdx.x] - v;
    if (threadIdx.x == 255) bsum[blockIdx.x] = sh[255];
}

// ---------- scan phase 2+3 + gstart fused ----------
__global__ __launch_bounds__(256) void scan3(const int* escan, const int* bsum,
        const int* batch, const int* flags, int* rowstart, int* cursor, int* gstart) {
    __shared__ int sb[256];
    int t = threadIdx.x;
    int v = (t < NBLK) ? bsum[t] : 0;
    sb[t] = v;
    __syncthreads();
    for (int off = 1; off < 256; off <<= 1) {
        int a = (t >= off) ? sb[t - off] : 0;
        __syncthreads();
        sb[t] += a;
        __syncthreads();
    }
    int boff = (blockIdx.x == 0) ? 0 : sb[blockIdx.x - 1];
    int i = blockIdx.x * 256 + t;
    if (i < NN) {
        int r = escan[i] + boff;
        rowstart[i] = r;
        cursor[i]   = r;
    }
    if (i == 0) rowstart[NN] = EETOT;
    // graph boundaries (batch sorted)
    if (i < NN) {
        int is64 = flags[13];
        int bc = ld_idx(batch, i, is64);
        if (i == 0) {
            for (int g = 0; g <= bc; ++g) gstart[g] = 0;
        } else {
            int bp = ld_idx(batch, i - 1, is64);
            for (int g = bp + 1; g <= bc; ++g) gstart[g] = i;
        }
        if (i == NN - 1) {
            for (int g = bc + 1; g <= NG; ++g) gstart[g] = NN;
        }
    }
}

// ---------- CSR fill: 4 B records {src:16 | bf16(norm):16} ----------
__global__ __launch_bounds__(256) void fill_kernel(const int* ei, const int* flags,
        const float* dinv, int* cursor, unsigned int* cv) {
    int e = blockIdx.x * 256 + threadIdx.x;
    if (e >= EETOT) return;
    int is64 = flags[12];
    int s, d;
    if (e < NE) { s = ld_idx(ei, e, is64); d = ld_idx(ei, NE + e, is64); }
    else        { s = d = e - NE; }
    int pos = atomicAdd(&cursor[d], 1);
    cv[pos] = (unsigned int)s | ((unsigned int)f2bf(dinv[s] * dinv[d]) << 16);
}

// ---------- MFMA GEMM: C[NN][128] = A[NN][128] @ W[128][128], all bf16 ----------
__global__ __launch_bounds__(256) void gemm_mfma(const unsigned int* __restrict__ A,
        const unsigned int* __restrict__ Wt, unsigned short* __restrict__ C) {
    int wave = threadIdx.x >> 6;
    int lane = threadIdx.x & 63;
    int quad = lane >> 4;
    int l16  = lane & 15;
    int mbase = blockIdx.x * 64 + wave * 16;
    int ra = mbase + l16;
    if (ra >= NN) ra = NN - 1;
    short8 af[4];
    const uint4* Arow = (const uint4*)(A + (size_t)ra * FDH);
    #pragma unroll
    for (int kk = 0; kk < 4; ++kk) {
        uint4 v = Arow[kk * 4 + quad];
        af[kk] = *(short8*)&v;
    }
    #pragma unroll
    for (int nt = 0; nt < 8; ++nt) {
        int n = nt * 16 + l16;
        const uint4* Wrow = (const uint4*)(Wt + (size_t)n * FDH);
        f32x4 acc = {0.f, 0.f, 0.f, 0.f};
        #pragma unroll
        for (int kk = 0; kk < 4; ++kk) {
            uint4 wv = Wrow[kk * 4 + quad];
            short8 bf = *(short8*)&wv;
            acc = __builtin_amdgcn_mfma_f32_16x16x32_bf16(af[kk], bf, acc, 0, 0, 0);
        }
        int row0 = mbase + quad * 4;
        #pragma unroll
        for (int reg = 0; reg < 4; ++reg) {
            int r = row0 + reg;
            if (r < NN) C[(size_t)r * FD + nt * 16 + l16] = f2bf(acc[reg]);
        }
    }
}

// ---------- CSR aggregation (bf16 gather, unroll 8) + bias + relu -> bf16 ----------
__global__ __launch_bounds__(256) void aggregate_kernel(const unsigned int* Hb,
        const unsigned int* cv, const int* rowstart, const float* bias,
        unsigned int* outb) {
    int n = blockIdx.x * 4 + (threadIdx.x >> 6);
    int cp = threadIdx.x & 63;
    if (n >= NN) return;
    int jb = rowstart[n], je = rowstart[n + 1];
    float acc0 = 0.f, acc1 = 0.f;
    int j = jb;
    for (; j + 7 < je; j += 8) {
        unsigned int rr[8], hh[8];
        #pragma unroll
        for (int k = 0; k < 8; ++k) rr[k] = cv[j + k];
        #pragma unroll
        for (int k = 0; k < 8; ++k) hh[k] = Hb[(size_t)(rr[k] & 0xFFFFu) * FDH + cp];
        #pragma unroll
        for (int k = 0; k < 8; ++k) {
            float v = bfbits((unsigned short)(rr[k] >> 16));
            acc0 += v * bflo(hh[k]);
            acc1 += v * bfhi(hh[k]);
        }
    }
    for (; j + 3 < je; j += 4) {
        unsigned int rr[4], hh[4];
        #pragma unroll
        for (int k = 0; k < 4; ++k) rr[k] = cv[j + k];
        #pragma unroll
        for (int k = 0; k < 4; ++k) hh[k] = Hb[(size_t)(rr[k] & 0xFFFFu) * FDH + cp];
        #pragma unroll
        for (int k = 0; k < 4; ++k) {
            float v = bfbits((unsigned short)(rr[k] >> 16));
            acc0 += v * bflo(hh[k]);
            acc1 += v * bfhi(hh[k]);
        }
    }
    for (; j < je; ++j) {
        unsigned int r = cv[j];
        unsigned int h = Hb[(size_t)(r & 0xFFFFu) * FDH + cp];
        float v = bfbits((unsigned short)(r >> 16));
        acc0 += v * bflo(h);
        acc1 += v * bfhi(h);
    }
    acc0 = fmaxf(acc0 + bias[2 * cp], 0.f);
    acc1 = fmaxf(acc1 + bias[2 * cp + 1], 0.f);
    outb[(size_t)n * FDH + cp] = packbf(acc0, acc1);
}

// ---------- pool partials: 8 slices per graph ----------
__global__ __launch_bounds__(64) void pool_part(const unsigned int* Hb,
        const int* gstart, float* part) {
    int g = blockIdx.x >> 3;
    int k = blockIdx.x & (PK - 1);
    int cp = threadIdx.x;
    int s = gstart[g], e = gstart[g + 1];
    int len = e - s;
    int per = (len + PK - 1) / PK;
    int ss = s + k * per;
    int ee = ss + per; if (ee > e) ee = e;
    float a0 = 0.f, a1 = 0.f, b0 = 0.f, b1 = 0.f;
    int n = ss;
    for (; n + 1 < ee; n += 2) {
        unsigned int h0 = Hb[(size_t)n * FDH + cp];
        unsigned int h1 = Hb[(size_t)(n + 1) * FDH + cp];
        a0 += bflo(h0); a1 += bfhi(h0);
        b0 += bflo(h1); b1 += bfhi(h1);
    }
    if (n < ee) {
        unsigned int h0 = Hb[(size_t)n * FDH + cp];
        a0 += bflo(h0); a1 += bfhi(h0);
    }
    part[(size_t)(g * PK + k) * FD + 2 * cp]     = a0 + b0;
    part[(size_t)(g * PK + k) * FD + 2 * cp + 1] = a1 + b1;
}

// ---------- head (+ partial reduce fused) ----------
__global__ __launch_bounds__(128) void head_kernel(const float* part, const int* gstart,
        const float* addf, const float* fc1w, const float* fc1b,
        const float* fc2w, const float* fc2b, const int* flags, void* outp) {
    int g = blockIdx.x;
    int t = threadIdx.x;
    __shared__ float z[FD + FA];
    __shared__ float h[FD];
    float a = 0.f;
    #pragma unroll
    for (int k = 0; k < PK; ++k) a += part[(size_t)(g * PK + k) * FD + t];
    float cnt = (float)(gstart[g + 1] - gstart[g]);
    if (cnt < 1.0f) cnt = 1.0f;
    z[t] = a / cnt;
    if (t < FA) z[FD + t] = addf[g * FA + t];
    __syncthreads();
    float acc = fc1b[t];
    #pragma unroll 4
    for (int k = 0; k < FD + FA; ++k)
        acc += z[k] * fc1w[k * FD + t];
    h[t] = fmaxf(acc, 0.f);
    __syncthreads();
    if (t < 2) {
        float o = fc2b[t];
        for (int j = 0; j < FD; ++j) o += h[j] * fc2w[j * 2 + t];
        if (flags[0]) ((unsigned short*)outp)[g * 2 + t] = f2bf(o);
        else          ((float*)outp)[g * 2 + t] = o;
    }
}

extern "C" void kernel_launch(void* const* d_in, const int* in_sizes, int n_in,
                              void* d_out, int out_size, void* d_ws, size_t ws_size,
                              hipStream_t stream) {
    (void)out_size;

    if (n_in != 12) {
        hipLaunchKernelGGL(mark_kernel, dim3(1), dim3(128), 0, stream,
                           (float*)d_out, 2000.0f);
        return;
    }
    const int exp_sizes[12] = {6400000, 1600000, 50000, 4096, 16384, 128,
                               16384, 128, 20480, 128, 256, 2};
    for (int i = 0; i < 12; ++i) {
        if (in_sizes[i] != exp_sizes[i]) {
            hipLaunchKernelGGL(mark_kernel, dim3(1), dim3(128), 0, stream,
                               (float*)d_out, 3000.0f + 100.0f * i);
            return;
        }
    }

    size_t off = 0;
    char* base = (char*)d_ws;
#define WSALLOC(ptr, type, nbytes) \
    type* ptr = (type*)(base + off); off += (((size_t)(nbytes)) + 255) & ~(size_t)255;
    WSALLOC(bufA,  unsigned int, (size_t)NN * FDH * 4)   // packed bf16 H
    WSALLOC(bufB,  unsigned int, (size_t)NN * FDH * 4)
    WSALLOC(bufC,  unsigned int, (size_t)NN * FDH * 4)   // x packed bf16
    WSALLOC(dinv,  float, (size_t)NN * 4)
    WSALLOC(degi,  int,   (size_t)NN * 4)
    WSALLOC(rowst, int,   (size_t)(NN + 1) * 4)
    WSALLOC(cursor,int,   (size_t)NN * 4)
    WSALLOC(escan, int,   (size_t)NN * 4)
    WSALLOC(bsum,  int,   (size_t)NBLK * 4)
    WSALLOC(cv,    unsigned int, (size_t)EETOT * 4)      // 4 B records
    WSALLOC(part,  float, (size_t)NG * PK * FD * 4)
    WSALLOC(gstart,int,   (size_t)(NG + 1) * 4)
    WSALLOC(W1t,   unsigned int, (size_t)FD * FDH * 4)
    WSALLOC(W2t,   unsigned int, (size_t)FD * FDH * 4)
    WSALLOC(b1f,   float, FD * 4)
    WSALLOC(b2f,   float, FD * 4)
    WSALLOC(addff, float, (size_t)NG * FA * 4)
    WSALLOC(fc1wf, float, (size_t)(FD + FA) * FD * 4)
    WSALLOC(fc1bf, float, FD * 4)
    WSALLOC(fc2wf, float, FD * 2 * 4)
    WSALLOC(fc2bf, float, 2 * 4)
    WSALLOC(flags, int, 16 * 4)
#undef WSALLOC
    if (ws_size < off) {
        hipLaunchKernelGGL(mark_kernel, dim3(1), dim3(128), 0, stream,
                           (float*)d_out, 1000.0f);
        return;
    }

    const int* ei    = (const int*)d_in[1];
    const int* batch = (const int*)d_in[2];

    hipLaunchKernelGGL(prep, dim3(12860), dim3(256), 0, stream,
                       d_in[0], ei, batch, d_in[3], d_in[4], d_in[5], d_in[6],
                       d_in[7], d_in[8], d_in[9], d_in[10], d_in[11],
                       bufC, W1t, W2t, addff, b1f, b2f, fc1wf, fc1bf,
                       fc2wf, fc2bf, flags, degi);

    hipLaunchKernelGGL(deg_kernel, dim3((NE + 255) / 256), dim3(256), 0, stream,
                       ei, flags, degi);
    hipLaunchKernelGGL(scan1, dim3(NBLK), dim3(256), 0, stream,
                       degi, dinv, escan, bsum);
    hipLaunchKernelGGL(scan3, dim3(NBLK), dim3(256), 0, stream,
                       escan, bsum, batch, flags, rowst, cursor, gstart);
    hipLaunchKernelGGL(fill_kernel, dim3((EETOT + 255) / 256), dim3(256), 0, stream,
                       ei, flags, dinv, cursor, cv);

    hipLaunchKernelGGL(gemm_mfma, dim3((NN + 63) / 64), dim3(256), 0, stream,
                       bufC, W1t, (unsigned short*)bufA);
    hipLaunchKernelGGL(aggregate_kernel, dim3((NN + 3) / 4), dim3(256), 0, stream,
                       bufA, cv, rowst, b1f, bufB);
    hipLaunchKernelGGL(gemm_mfma, dim3((NN + 63) / 64), dim3(256), 0, stream,
                       bufB, W2t, (unsigned short*)bufA);
    hipLaunchKernelGGL(aggregate_kernel, dim3((NN + 3) / 4), dim3(256), 0, stream,
                       bufA, cv, rowst, b2f, bufB);

    hipLaunchKernelGGL(pool_part, dim3(NG * PK), dim3(64), 0, stream,
                       bufB, gstart, part);
    hipLaunchKernelGGL(head_kernel, dim3(NG), dim3(FD), 0, stream,
                       part, gstart, addff, fc1wf, fc1bf, fc2wf, fc2bf,
                       flags, d_out);
}

// Round 15
// 339.021 us; speedup vs baseline: 3.0030x; 1.0157x over previous
//
#include <hip/hip_runtime.h>

#define NN 50000
#define NE 800000
#define FD 128
#define FDH 64            // FD/2 packed bf16 pairs
#define FA 32
#define NG 128
#define EETOT (NE + NN)
#define NBLK ((NN + 255) / 256)   // 196 scan blocks
#define PK 8                      // pool partial slices per graph
#define FEPB 2048                 // fill: edges per chunk
#define FNCH ((EETOT + FEPB - 1) / FEPB)
#define NPXCD 6250                // nodes per XCD-parity bin (8*6250 = 50000)

typedef __attribute__((ext_vector_type(8))) short short8;
typedef __attribute__((ext_vector_type(4))) float f32x4;

// ---------- bf16 helpers ----------
__device__ __forceinline__ float bfbits(unsigned short u) {
    return __uint_as_float(((unsigned int)u) << 16);
}
__device__ __forceinline__ float bflo(unsigned int p) { return __uint_as_float(p << 16); }
__device__ __forceinline__ float bfhi(unsigned int p) { return __uint_as_float(p & 0xffff0000u); }
__device__ __forceinline__ unsigned short f2bf(float f) {   // RNE
    unsigned int u = __float_as_uint(f);
    unsigned int r = u + 0x7FFFu + ((u >> 16) & 1u);
    return (unsigned short)(r >> 16);
}
__device__ __forceinline__ unsigned int packbf(float a, float b) {
    return (unsigned int)f2bf(a) | ((unsigned int)f2bf(b) << 16);
}
__device__ __forceinline__ int ld_idx(const int* p, int i, int is64) {
    return is64 ? p[2 * i] : p[i];
}
__device__ int probe_bf16(const unsigned int* t, int nwords) {
    int nz = 0, hits = 0;
    for (int i = 0; i < nwords; ++i) {
        unsigned int w = t[i];
        if (w == 0u) continue;
        ++nz;
        unsigned int e = (w >> 7) & 0xFFu;
        if (e >= 100u && e <= 140u) ++hits;
    }
    return (nz < 8) ? 1 : (hits * 4 >= nz * 3);
}

// ---------- sentinels ----------
__global__ __launch_bounds__(128) void mark_kernel(float* out, float v) {
    out[threadIdx.x] = v;
}

// ---------- all dtype probes once ----------
__global__ __launch_bounds__(64) void flags_kernel(
        const unsigned int* x, const int* ei, const int* batch,
        const unsigned int* addf, const unsigned int* w1, const unsigned int* b1,
        const unsigned int* w2, const unsigned int* b2, const unsigned int* fc1w,
        const unsigned int* fc1b, const unsigned int* fc2w, const unsigned int* fc2b,
        int* flags) {
    if (threadIdx.x != 0) return;
    flags[0]  = probe_bf16(x, 64);
    flags[3]  = probe_bf16(addf, 64);
    flags[4]  = probe_bf16(w1, 64);
    flags[5]  = probe_bf16(b1, 64);
    flags[6]  = probe_bf16(w2, 64);
    flags[7]  = probe_bf16(b2, 64);
    flags[8]  = probe_bf16(fc1w, 64);
    flags[9]  = probe_bf16(fc1b, 64);
    flags[10] = probe_bf16(fc2w, 64);
    flags[11] = probe_bf16(fc2b, 1);
    int odd_or = 0;
    for (int k = 0; k < 32; ++k) odd_or |= ei[2 * k + 1];
    flags[12] = (odd_or == 0) ? 1 : 0;
    flags[13] = (batch[NN - 1] == 0) ? 1 : 0;
}

// ---------- fused prep: canonicalize everything + zero degi (flags precomputed) ----------
// blocks [0,12500): x -> packed bf16 bufC
// blocks [12500,12564): W1/W2 -> transposed packed bf16
// blocks [12564,12663): all fp32-dest weights
// blocks [12663,12859): zero degi
__global__ __launch_bounds__(256) void prep(
        const void* x, const void* addf,
        const void* w1, const void* b1, const void* w2, const void* b2,
        const void* fc1w, const void* fc1b, const void* fc2w, const void* fc2b,
        unsigned int* bufC, unsigned int* W1t, unsigned int* W2t,
        float* addff, float* b1f, float* b2f, float* fc1wf, float* fc1bf,
        float* fc2wf, float* fc2bf, const int* flags, int* degi) {
    int b = blockIdx.x;
    if (b < 12500) {
        int i = b * 256 + threadIdx.x;           // < NN*FDH = 3.2M
        if (flags[0]) {
            bufC[i] = ((const unsigned int*)x)[i];
        } else {
            const float* s = (const float*)x;
            bufC[i] = packbf(s[2 * i], s[2 * i + 1]);
        }
    } else if (b < 12564) {
        int rel = (b - 12500) * 256 + threadIdx.x;   // [0,16384)
        const void* src = (rel < 8192) ? w1 : w2;
        unsigned int* dst = (rel < 8192) ? W1t : W2t;
        int flag = (rel < 8192) ? flags[4] : flags[6];
        int rr = rel & 8191;
        int n = rr >> 6, kk = rr & 63;
        float lo, hi;
        if (flag) {
            const unsigned short* s = (const unsigned short*)src;
            lo = bfbits(s[(2 * kk) * FD + n]);
            hi = bfbits(s[(2 * kk + 1) * FD + n]);
        } else {
            const float* s = (const float*)src;
            lo = s[(2 * kk) * FD + n];
            hi = s[(2 * kk + 1) * FD + n];
        }
        dst[rr] = packbf(lo, hi);
    } else if (b < 12663) {
        int i = (b - 12564) * 256 + threadIdx.x;     // [0,25344)
        const void* src; float* dst; int flag; int rel;
        if      (i < 4096)  { src = addf; dst = addff; flag = flags[3];  rel = i; }
        else if (i < 4224)  { src = b1;   dst = b1f;   flag = flags[5];  rel = i - 4096; }
        else if (i < 4352)  { src = b2;   dst = b2f;   flag = flags[7];  rel = i - 4224; }
        else if (i < 24832) { src = fc1w; dst = fc1wf; flag = flags[8];  rel = i - 4352; }
        else if (i < 24960) { src = fc1b; dst = fc1bf; flag = flags[9];  rel = i - 24832; }
        else if (i < 25216) { src = fc2w; dst = fc2wf; flag = flags[10]; rel = i - 24960; }
        else if (i < 25218) { src = fc2b; dst = fc2bf; flag = flags[11]; rel = i - 25216; }
        else return;
        if (flag) dst[rel] = bfbits(((const unsigned short*)src)[rel]);
        else      dst[rel] = ((const float*)src)[rel];
    } else {
        int i = (b - 12663) * 256 + threadIdx.x;
        if (i < NN) degi[i] = 0;
    }
}

// ---------- degree ----------
__global__ __launch_bounds__(256) void deg_kernel(const int* ei, const int* flags,
                                                  int* deg) {
    int e = blockIdx.x * 256 + threadIdx.x;
    int is64 = flags[12];
    if (e < NE) atomicAdd(&deg[ld_idx(ei, NE + e, is64)], 1);
}

// ---------- scan phase 1 (+ dinv fused) ----------
__global__ __launch_bounds__(256) void scan1(const int* deg, float* dinv,
                                             int* escan, int* bsum) {
    __shared__ int sh[256];
    int i = blockIdx.x * 256 + threadIdx.x;
    int d = (i < NN) ? deg[i] : 0;
    if (i < NN) dinv[i] = rsqrtf((float)(d + 1));
    int v = (i < NN) ? d + 1 : 0;
    sh[threadIdx.x] = v;
    __syncthreads();
    for (int off = 1; off < 256; off <<= 1) {
        int a = ((int)threadIdx.x >= off) ? sh[threadIdx.x - off] : 0;
        __syncthreads();
        sh[threadIdx.x] += a;
        __syncthreads();
    }
    if (i < NN) escan[i] = sh[threadIdx.x] - v;
    if (threadIdx.x == 255) bsum[blockIdx.x] = sh[255];
}

// ---------- scan phase 2+3 + gstart fused ----------
__global__ __launch_bounds__(256) void scan3(const int* escan, const int* bsum,
        const int* batch, const int* flags, int* rowstart, int* cursor, int* gstart) {
    __shared__ int sb[256];
    int t = threadIdx.x;
    int v = (t < NBLK) ? bsum[t] : 0;
    sb[t] = v;
    __syncthreads();
    for (int off = 1; off < 256; off <<= 1) {
        int a = (t >= off) ? sb[t - off] : 0;
        __syncthreads();
        sb[t] += a;
        __syncthreads();
    }
    int boff = (blockIdx.x == 0) ? 0 : sb[blockIdx.x - 1];
    int i = blockIdx.x * 256 + t;
    if (i < NN) {
        int r = escan[i] + boff;
        rowstart[i] = r;
        cursor[i]   = r;
    }
    if (i == 0) rowstart[NN] = EETOT;
    if (i < NN) {
        int is64 = flags[13];
        int bc = ld_idx(batch, i, is64);
        if (i == 0) {
            for (int g = 0; g <= bc; ++g) gstart[g] = 0;
        } else {
            int bp = ld_idx(batch, i - 1, is64);
            for (int g = bp + 1; g <= bc; ++g) gstart[g] = i;
        }
        if (i == NN - 1) {
            for (int g = bc + 1; g <= NG; ++g) gstart[g] = NN;
        }
    }
}

// ---------- CSR fill with XCD-affinity dst binning ----------
// block b: chunk = b>>3, parity p = b&7. Processes edges of its chunk whose
// dst/6250 == p. If blockIdx%8 -> XCD round-robin holds, all writes to a cv
// line come from one XCD and merge in its L2 (cv slice per parity ~425 KB).
__global__ __launch_bounds__(256) void fill_kernel(const int* ei, const int* flags,
        const float* dinv, int* cursor, unsigned int* cv) {
    int chunk = blockIdx.x >> 3;
    int par   = blockIdx.x & 7;
    int base  = chunk * FEPB;
    int is64  = flags[12];
    #pragma unroll
    for (int k = 0; k < FEPB / 256; ++k) {
        int e = base + k * 256 + threadIdx.x;
        if (e >= EETOT) break;
        int s, d;
        if (e < NE) { d = ld_idx(ei, NE + e, is64); s = -1; }
        else        { s = d = e - NE; }
        if (d / NPXCD != par) continue;
        if (s < 0) s = ld_idx(ei, e, is64);
        int pos = atomicAdd(&cursor[d], 1);
        cv[pos] = (unsigned int)s | ((unsigned int)f2bf(dinv[s] * dinv[d]) << 16);
    }
}

// ---------- MFMA GEMM: C[NN][128] = A[NN][128] @ W[128][128], all bf16 ----------
__global__ __launch_bounds__(256) void gemm_mfma(const unsigned int* __restrict__ A,
        const unsigned int* __restrict__ Wt, unsigned short* __restrict__ C) {
    int wave = threadIdx.x >> 6;
    int lane = threadIdx.x & 63;
    int quad = lane >> 4;
    int l16  = lane & 15;
    int mbase = blockIdx.x * 64 + wave * 16;
    int ra = mbase + l16;
    if (ra >= NN) ra = NN - 1;
    short8 af[4];
    const uint4* Arow = (const uint4*)(A + (size_t)ra * FDH);
    #pragma unroll
    for (int kk = 0; kk < 4; ++kk) {
        uint4 v = Arow[kk * 4 + quad];
        af[kk] = *(short8*)&v;
    }
    #pragma unroll
    for (int nt = 0; nt < 8; ++nt) {
        int n = nt * 16 + l16;
        const uint4* Wrow = (const uint4*)(Wt + (size_t)n * FDH);
        f32x4 acc = {0.f, 0.f, 0.f, 0.f};
        #pragma unroll
        for (int kk = 0; kk < 4; ++kk) {
            uint4 wv = Wrow[kk * 4 + quad];
            short8 bf = *(short8*)&wv;
            acc = __builtin_amdgcn_mfma_f32_16x16x32_bf16(af[kk], bf, acc, 0, 0, 0);
        }
        int row0 = mbase + quad * 4;
        #pragma unroll
        for (int reg = 0; reg < 4; ++reg) {
            int r = row0 + reg;
            if (r < NN) C[(size_t)r * FD + nt * 16 + l16] = f2bf(acc[reg]);
        }
    }
}

// ---------- CSR aggregation (bf16 gather, unroll 8) + bias + relu -> bf16 ----------
__global__ __launch_bounds__(256) void aggregate_kernel(const unsigned int* Hb,
        const unsigned int* cv, const int* rowstart, const float* bias,
        unsigned int* outb) {
    int n = blockIdx.x * 4 + (threadIdx.x >> 6);
    int cp = threadIdx.x & 63;
    if (n >= NN) return;
    int jb = rowstart[n], je = rowstart[n + 1];
    float acc0 = 0.f, acc1 = 0.f;
    int j = jb;
    for (; j + 7 < je; j += 8) {
        unsigned int rr[8], hh[8];
        #pragma unroll
        for (int k = 0; k < 8; ++k) rr[k] = cv[j + k];
        #pragma unroll
        for (int k = 0; k < 8; ++k) hh[k] = Hb[(size_t)(rr[k] & 0xFFFFu) * FDH + cp];
        #pragma unroll
        for (int k = 0; k < 8; ++k) {
            float v = bfbits((unsigned short)(rr[k] >> 16));
            acc0 += v * bflo(hh[k]);
            acc1 += v * bfhi(hh[k]);
        }
    }
    for (; j + 3 < je; j += 4) {
        unsigned int rr[4], hh[4];
        #pragma unroll
        for (int k = 0; k < 4; ++k) rr[k] = cv[j + k];
        #pragma unroll
        for (int k = 0; k < 4; ++k) hh[k] = Hb[(size_t)(rr[k] & 0xFFFFu) * FDH + cp];
        #pragma unroll
        for (int k = 0; k < 4; ++k) {
            float v = bfbits((unsigned short)(rr[k] >> 16));
            acc0 += v * bflo(hh[k]);
            acc1 += v * bfhi(hh[k]);
        }
    }
    for (; j < je; ++j) {
        unsigned int r = cv[j];
        unsigned int h = Hb[(size_t)(r & 0xFFFFu) * FDH + cp];
        float v = bfbits((unsigned short)(r >> 16));
        acc0 += v * bflo(h);
        acc1 += v * bfhi(h);
    }
    acc0 = fmaxf(acc0 + bias[2 * cp], 0.f);
    acc1 = fmaxf(acc1 + bias[2 * cp + 1], 0.f);
    outb[(size_t)n * FDH + cp] = packbf(acc0, acc1);
}

// ---------- pool partials: 8 slices per graph ----------
__global__ __launch_bounds__(64) void pool_part(const unsigned int* Hb,
        const int* gstart, float* part) {
    int g = blockIdx.x >> 3;
    int k = blockIdx.x & (PK - 1);
    int cp = threadIdx.x;
    int s = gstart[g], e = gstart[g + 1];
    int len = e - s;
    int per = (len + PK - 1) / PK;
    int ss = s + k * per;
    int ee = ss + per; if (ee > e) ee = e;
    float a0 = 0.f, a1 = 0.f, b0 = 0.f, b1 = 0.f;
    int n = ss;
    for (; n + 1 < ee; n += 2) {
        unsigned int h0 = Hb[(size_t)n * FDH + cp];
        unsigned int h1 = Hb[(size_t)(n + 1) * FDH + cp];
        a0 += bflo(h0); a1 += bfhi(h0);
        b0 += bflo(h1); b1 += bfhi(h1);
    }
    if (n < ee) {
        unsigned int h0 = Hb[(size_t)n * FDH + cp];
        a0 += bflo(h0); a1 += bfhi(h0);
    }
    part[(size_t)(g * PK + k) * FD + 2 * cp]     = a0 + b0;
    part[(size_t)(g * PK + k) * FD + 2 * cp + 1] = a1 + b1;
}

// ---------- head (+ partial reduce fused) ----------
__global__ __launch_bounds__(128) void head_kernel(const float* part, const int* gstart,
        const float* addf, const float* fc1w, const float* fc1b,
        const float* fc2w, const float* fc2b, const int* flags, void* outp) {
    int g = blockIdx.x;
    int t = threadIdx.x;
    __shared__ float z[FD + FA];
    __shared__ float h[FD];
    float a = 0.f;
    #pragma unroll
    for (int k = 0; k < PK; ++k) a += part[(size_t)(g * PK + k) * FD + t];
    float cnt = (float)(gstart[g + 1] - gstart[g]);
    if (cnt < 1.0f) cnt = 1.0f;
    z[t] = a / cnt;
    if (t < FA) z[FD + t] = addf[g * FA + t];
    __syncthreads();
    float acc = fc1b[t];
    #pragma unroll 4
    for (int k = 0; k < FD + FA; ++k)
        acc += z[k] * fc1w[k * FD + t];
    h[t] = fmaxf(acc, 0.f);
    __syncthreads();
    if (t < 2) {
        float o = fc2b[t];
        for (int j = 0; j < FD; ++j) o += h[j] * fc2w[j * 2 + t];
        if (flags[0]) ((unsigned short*)outp)[g * 2 + t] = f2bf(o);
        else          ((float*)outp)[g * 2 + t] = o;
    }
}

extern "C" void kernel_launch(void* const* d_in, const int* in_sizes, int n_in,
                              void* d_out, int out_size, void* d_ws, size_t ws_size,
                              hipStream_t stream) {
    (void)out_size;

    if (n_in != 12) {
        hipLaunchKernelGGL(mark_kernel, dim3(1), dim3(128), 0, stream,
                           (float*)d_out, 2000.0f);
        return;
    }
    const int exp_sizes[12] = {6400000, 1600000, 50000, 4096, 16384, 128,
                               16384, 128, 20480, 128, 256, 2};
    for (int i = 0; i < 12; ++i) {
        if (in_sizes[i] != exp_sizes[i]) {
            hipLaunchKernelGGL(mark_kernel, dim3(1), dim3(128), 0, stream,
                               (float*)d_out, 3000.0f + 100.0f * i);
            return;
        }
    }

    size_t off = 0;
    char* base = (char*)d_ws;
#define WSALLOC(ptr, type, nbytes) \
    type* ptr = (type*)(base + off); off += (((size_t)(nbytes)) + 255) & ~(size_t)255;
    WSALLOC(bufA,  unsigned int, (size_t)NN * FDH * 4)
    WSALLOC(bufB,  unsigned int, (size_t)NN * FDH * 4)
    WSALLOC(bufC,  unsigned int, (size_t)NN * FDH * 4)
    WSALLOC(dinv,  float, (size_t)NN * 4)
    WSALLOC(degi,  int,   (size_t)NN * 4)
    WSALLOC(rowst, int,   (size_t)(NN + 1) * 4)
    WSALLOC(cursor,int,   (size_t)NN * 4)
    WSALLOC(escan, int,   (size_t)NN * 4)
    WSALLOC(bsum,  int,   (size_t)NBLK * 4)
    WSALLOC(cv,    unsigned int, (size_t)EETOT * 4)
    WSALLOC(part,  float, (size_t)NG * PK * FD * 4)
    WSALLOC(gstart,int,   (size_t)(NG + 1) * 4)
    WSALLOC(W1t,   unsigned int, (size_t)FD * FDH * 4)
    WSALLOC(W2t,   unsigned int, (size_t)FD * FDH * 4)
    WSALLOC(b1f,   float, FD * 4)
    WSALLOC(b2f,   float, FD * 4)
    WSALLOC(addff, float, (size_t)NG * FA * 4)
    WSALLOC(fc1wf, float, (size_t)(FD + FA) * FD * 4)
    WSALLOC(fc1bf, float, FD * 4)
    WSALLOC(fc2wf, float, FD * 2 * 4)
    WSALLOC(fc2bf, float, 2 * 4)
    WSALLOC(flags, int, 16 * 4)
#undef WSALLOC
    if (ws_size < off) {
        hipLaunchKernelGGL(mark_kernel, dim3(1), dim3(128), 0, stream,
                           (float*)d_out, 1000.0f);
        return;
    }

    const int* ei    = (const int*)d_in[1];
    const int* batch = (const int*)d_in[2];

    hipLaunchKernelGGL(flags_kernel, dim3(1), dim3(64), 0, stream,
                       (const unsigned int*)d_in[0], ei, batch,
                       (const unsigned int*)d_in[3], (const unsigned int*)d_in[4],
                       (const unsigned int*)d_in[5], (const unsigned int*)d_in[6],
                       (const unsigned int*)d_in[7], (const unsigned int*)d_in[8],
                       (const unsigned int*)d_in[9], (const unsigned int*)d_in[10],
                       (const unsigned int*)d_in[11], flags);

    hipLaunchKernelGGL(prep, dim3(12859), dim3(256), 0, stream,
                       d_in[0], d_in[3], d_in[4], d_in[5], d_in[6],
                       d_in[7], d_in[8], d_in[9], d_in[10], d_in[11],
                       bufC, W1t, W2t, addff, b1f, b2f, fc1wf, fc1bf,
                       fc2wf, fc2bf, flags, degi);

    hipLaunchKernelGGL(deg_kernel, dim3((NE + 255) / 256), dim3(256), 0, stream,
                       ei, flags, degi);
    hipLaunchKernelGGL(scan1, dim3(NBLK), dim3(256), 0, stream,
                       degi, dinv, escan, bsum);
    hipLaunchKernelGGL(scan3, dim3(NBLK), dim3(256), 0, stream,
                       escan, bsum, batch, flags, rowst, cursor, gstart);
    hipLaunchKernelGGL(fill_kernel, dim3(FNCH * 8), dim3(256), 0, stream,
                       ei, flags, dinv, cursor, cv);

    hipLaunchKernelGGL(gemm_mfma, dim3((NN + 63) / 64), dim3(256), 0, stream,
                       bufC, W1t, (unsigned short*)bufA);
    hipLaunchKernelGGL(aggregate_kernel, dim3((NN + 3) / 4), dim3(256), 0, stream,
                       bufA, cv, rowst, b1f, bufB);
    hipLaunchKernelGGL(gemm_mfma, dim3((NN + 63) / 64), dim3(256), 0, stream,
                       bufB, W2t, (unsigned short*)bufA);
    hipLaunchKernelGGL(aggregate_kernel, dim3((NN + 3) / 4), dim3(256), 0, stream,
                       bufA, cv, rowst, b2f, bufB);

    hipLaunchKernelGGL(pool_part, dim3(NG * PK), dim3(64), 0, stream,
                       bufB, gstart, part);
    hipLaunchKernelGGL(head_kernel, dim3(NG), dim3(FD), 0, stream,
                       part, gstart, addff, fc1wf, fc1bf, fc2wf, fc2bf,
                       flags, d_out);
}